// Round 1
// baseline (1192.563 us; speedup 1.0000x reference)
//
#include <hip/hip_runtime.h>
#include <math.h>

#define HD 64  // hidden dim H

// ---------------- init: cnt=1 (self loop), zero accumulators ----------------
__global__ void k_init(int* cnt, float* gacc, float* sE, int N) {
    int i = blockIdx.x * blockDim.x + threadIdx.x;
    if (i < N) cnt[i] = 1;
    if (i < HD) gacc[i] = 0.f;
    if (i < 3) sE[i] = 0.f;
}

// ---------------- u[l][f] = sum_h We_l[f*H+h] * ae_l[h] ----------------
__global__ void k_u(const float* We1, const float* ae1,
                    const float* We2, const float* ae2,
                    const float* We3, const float* ae3,
                    float* u, int FE) {
    int t = threadIdx.x;
    if (t < 3 * FE) {
        int l = t / FE, f = t % FE;
        const float* We = (l == 0) ? We1 : (l == 1) ? We2 : We3;
        const float* ae = (l == 0) ? ae1 : (l == 1) ? ae2 : ae3;
        float s = 0.f;
        for (int hh = 0; hh < HD; ++hh) s += We[f * HD + hh] * ae[hh];
        u[l * FE + f] = s;
    }
}

// ---------------- in-degree histogram over dst ----------------
__global__ void k_hist(const int* __restrict__ ei, int E, int* cnt) {
    int e = blockIdx.x * blockDim.x + threadIdx.x;
    if (e < E) atomicAdd(&cnt[ei[E + e]], 1);
}

// ---------------- single-block exclusive scan -> row_ptr, fill=row_ptr+1 ----------------
__global__ void k_scan(const int* __restrict__ cnt, int* row_ptr, int* fill, int N) {
    const int T = 256;
    __shared__ int sums[T];
    int t = threadIdx.x;
    int per = (N + T - 1) / T;
    int lo = t * per, hi = min(N, lo + per);
    int s = 0;
    for (int i = lo; i < hi; ++i) s += cnt[i];
    sums[t] = s;
    __syncthreads();
    for (int d = 1; d < T; d <<= 1) {
        int v = (t >= d) ? sums[t - d] : 0;
        __syncthreads();
        sums[t] += v;
        __syncthreads();
    }
    int run = sums[t] - s;  // exclusive prefix
    for (int i = lo; i < hi; ++i) {
        row_ptr[i] = run;
        fill[i] = run + 1;  // slot 0 of each segment reserved for the self-loop
        run += cnt[i];
    }
    if (t == T - 1) row_ptr[N] = run;
}

// ---------------- scatter edges into CSR; alphaE for 3 layers; sum alphaE ----------------
__global__ void k_scatter(const int* __restrict__ ei, const float* __restrict__ ea,
                          const float* __restrict__ u, int E, int Ep, int FE,
                          int* fill, int* csr_src, float* alphaE, float* sE) {
    int e = blockIdx.x * blockDim.x + threadIdx.x;
    float a0 = 0.f, a1 = 0.f, a2 = 0.f;
    bool active = (e < E);
    if (active) {
        int src = ei[e], dst = ei[E + e];
        for (int f = 0; f < FE; ++f) {
            float v = ea[(size_t)e * FE + f];
            a0 += v * u[f];
            a1 += v * u[FE + f];
            a2 += v * u[2 * FE + f];
        }
        int pos = atomicAdd(&fill[dst], 1);
        csr_src[pos] = src;
        alphaE[pos] = a0;
        alphaE[Ep + pos] = a1;
        alphaE[2 * Ep + pos] = a2;
    }
    // wave-reduce alphaE sums (for self-loop mean) -> 3 atomics per wave
    float v0 = active ? a0 : 0.f, v1 = active ? a1 : 0.f, v2 = active ? a2 : 0.f;
    for (int d = 32; d; d >>= 1) {
        v0 += __shfl_down(v0, d, 64);
        v1 += __shfl_down(v1, d, 64);
        v2 += __shfl_down(v2, d, 64);
    }
    if ((threadIdx.x & 63) == 0) {
        atomicAdd(&sE[0], v0);
        atomicAdd(&sE[1], v1);
        atomicAdd(&sE[2], v2);
    }
}

// ---------------- fill self-loop CSR slots ----------------
__global__ void k_self(const int* __restrict__ row_ptr, int* csr_src, float* alphaE,
                       const float* __restrict__ sE, int N, int Ep, float invE) {
    int n = blockIdx.x * blockDim.x + threadIdx.x;
    if (n < N) {
        int pos = row_ptr[n];
        csr_src[pos] = n;
        alphaE[pos] = sE[0] * invE;
        alphaE[Ep + pos] = sE[1] * invE;
        alphaE[2 * Ep + pos] = sE[2] * invE;
    }
}

// ---------------- h = x @ W ; as_n = h.a_s ; ad_n = h.a_d ----------------
// block = 256 threads, 16 nodes per block. LDS: W[K*64] + X[16*K]
__global__ void k_gemm(const float* __restrict__ x, const float* __restrict__ W,
                       const float* __restrict__ a_s, const float* __restrict__ a_d,
                       float* __restrict__ h, float* __restrict__ as_n,
                       float* __restrict__ ad_n, int N, int K) {
    extern __shared__ float lds[];
    float* Ws = lds;            // K*64
    float* Xs = lds + K * HD;   // 16*K
    int t = threadIdx.x;
    int nb = blockIdx.x * 16;
    for (int i = t; i < K * HD; i += 256) Ws[i] = W[i];
    for (int i = t; i < 16 * K; i += 256) {
        int r = i / K, c = i % K;
        int gr = nb + r;
        if (gr >= N) gr = N - 1;
        Xs[i] = x[(size_t)gr * K + c];
    }
    __syncthreads();
    int c = t & 63, w = t >> 6;
    float acc[4] = {0.f, 0.f, 0.f, 0.f};
    for (int k = 0; k < K; ++k) {
        float wv = Ws[k * HD + c];
#pragma unroll
        for (int j = 0; j < 4; ++j) acc[j] += Xs[(w * 4 + j) * K + k] * wv;
    }
    float asv = a_s[c], adv = a_d[c];
#pragma unroll
    for (int j = 0; j < 4; ++j) {
        int n = nb + w * 4 + j;
        if (n >= N) continue;
        h[(size_t)n * HD + c] = acc[j];
        float vs = acc[j] * asv, vd = acc[j] * adv;
        for (int d = 32; d; d >>= 1) {
            vs += __shfl_down(vs, d, 64);
            vd += __shfl_down(vd, d, 64);
        }
        if (c == 0) { as_n[n] = vs; ad_n[n] = vd; }
    }
}

// ---------------- per-node online-softmax aggregation (1 wave per node) ----------------
__global__ void k_aggr(const float* __restrict__ h, const float* __restrict__ as_n,
                       const float* __restrict__ ad_n, const int* __restrict__ row_ptr,
                       const int* __restrict__ csr_src, const float* __restrict__ aE,
                       const float* __restrict__ b, float* __restrict__ x_out,
                       float* __restrict__ emb, int N, int first) {
    int wave = threadIdx.x >> 6, f = threadIdx.x & 63;
    int n = blockIdx.x * 4 + wave;
    if (n >= N) return;
    int base = row_ptr[n], end = row_ptr[n + 1];
    float adv = ad_n[n];
    float m = -INFINITY, d = 0.f, acc = 0.f;
    for (int i = base; i < end; ++i) {
        int s = csr_src[i];
        float a = as_n[s] + adv + aE[i];
        a = (a > 0.f) ? a : 0.2f * a;
        float hv = h[(size_t)s * HD + f];
        float mn = fmaxf(m, a);
        float scale = __expf(m - mn);  // first iter: exp(-inf) = 0
        float wgt = __expf(a - mn);
        d = d * scale + wgt;
        acc = acc * scale + wgt * hv;
        m = mn;
    }
    float out = acc / (d + 1e-16f) + b[f];
    float v = (out > 0.f) ? out : expm1f(out);
    x_out[(size_t)n * HD + f] = v;
    if (first) emb[(size_t)n * HD + f] = v;
    else emb[(size_t)n * HD + f] += v;
}

// ---------------- column sums of emb -> gacc (atomic) ----------------
__global__ void k_red(const float* __restrict__ emb, float* gacc, int N) {
    __shared__ float lds[256];
    int f = threadIdx.x & 63, w = threadIdx.x >> 6;
    float s = 0.f;
    for (int n = blockIdx.x * 4 + w; n < N; n += gridDim.x * 4)
        s += emb[(size_t)n * HD + f];
    lds[threadIdx.x] = s;
    __syncthreads();
    if (w == 0) {
        float v = lds[f] + lds[64 + f] + lds[128 + f] + lds[192 + f];
        atomicAdd(&gacc[f], v);
    }
}

__global__ void k_div(const float* __restrict__ gacc, float* out, int N) {
    int f = threadIdx.x;
    if (f < HD) out[(size_t)N * HD + f] = gacc[f] / (float)N;
}

extern "C" void kernel_launch(void* const* d_in, const int* in_sizes, int n_in,
                              void* d_out, int out_size, void* d_ws, size_t ws_size,
                              hipStream_t stream) {
    const float* x = (const float*)d_in[0];
    const int* ei = (const int*)d_in[1];
    const float* ea = (const float*)d_in[2];

    const int FIN = in_sizes[3] / HD;       // W1 is [F_IN, 64]
    const int N = in_sizes[0] / FIN;
    const int E = in_sizes[1] / 2;
    const int FE = in_sizes[2] / E;
    const int Ep = E + N;

    // per-layer params: base 3 + 6*l : W, as, ad, We, ae, b
    const float* W[3];  const float* as_[3]; const float* ad_[3];
    const float* We[3]; const float* ae_[3]; const float* bb[3];
    for (int l = 0; l < 3; ++l) {
        W[l]  = (const float*)d_in[3 + 6 * l + 0];
        as_[l] = (const float*)d_in[3 + 6 * l + 1];
        ad_[l] = (const float*)d_in[3 + 6 * l + 2];
        We[l] = (const float*)d_in[3 + 6 * l + 3];
        ae_[l] = (const float*)d_in[3 + 6 * l + 4];
        bb[l] = (const float*)d_in[3 + 6 * l + 5];
    }

    // ---- workspace layout (bytes, 256-aligned) ----
    char* ws = (char*)d_ws;
    size_t off = 0;
    auto alloc = [&](size_t bytes) {
        void* p = ws + off;
        off += (bytes + 255) & ~(size_t)255;
        return p;
    };
    float* h      = (float*)alloc((size_t)N * HD * 4);
    float* x_cur  = (float*)alloc((size_t)N * HD * 4);
    float* as_n   = (float*)alloc((size_t)N * 4);
    float* ad_n   = (float*)alloc((size_t)N * 4);
    int*   cnt    = (int*)alloc((size_t)N * 4);
    int*   rowp   = (int*)alloc((size_t)(N + 1) * 4);
    int*   fill   = (int*)alloc((size_t)N * 4);
    int*   csrs   = (int*)alloc((size_t)Ep * 4);
    float* alphaE = (float*)alloc((size_t)3 * Ep * 4);
    float* u      = (float*)alloc((size_t)3 * FE * 4);
    float* sE     = (float*)alloc(3 * 4);
    float* gacc   = (float*)alloc(HD * 4);
    (void)ws_size; (void)n_in; (void)out_size;

    float* emb = (float*)d_out;  // [N,64] node embeddings; tail 64 = graph emb

    int gN = (N + 255) / 256;
    int gE = (E + 255) / 256;

    k_init<<<gN, 256, 0, stream>>>(cnt, gacc, sE, N);
    k_u<<<1, 64, 0, stream>>>(We[0], ae_[0], We[1], ae_[1], We[2], ae_[2], u, FE);
    k_hist<<<gE, 256, 0, stream>>>(ei, E, cnt);
    k_scan<<<1, 256, 0, stream>>>(cnt, rowp, fill, N);
    k_scatter<<<gE, 256, 0, stream>>>(ei, ea, u, E, Ep, FE, fill, csrs, alphaE, sE);
    k_self<<<gN, 256, 0, stream>>>(rowp, csrs, alphaE, sE, N, Ep, 1.0f / (float)E);

    for (int l = 0; l < 3; ++l) {
        const float* xin = (l == 0) ? x : x_cur;
        int K = (l == 0) ? FIN : HD;
        size_t ldsz = (size_t)(K * HD + 16 * K) * 4;
        k_gemm<<<(N + 15) / 16, 256, ldsz, stream>>>(xin, W[l], as_[l], ad_[l],
                                                     h, as_n, ad_n, N, K);
        k_aggr<<<(N + 3) / 4, 256, 0, stream>>>(h, as_n, ad_n, rowp, csrs,
                                                alphaE + (size_t)l * Ep, bb[l],
                                                x_cur, emb, N, (l == 0) ? 1 : 0);
    }

    k_red<<<256, 256, 0, stream>>>(emb, gacc, N);
    k_div<<<1, 64, 0, stream>>>(gacc, emb, N);
}

// Round 2
// 1081.799 us; speedup vs baseline: 1.1024x; 1.1024x over previous
//
#include <hip/hip_runtime.h>
#include <math.h>

#define HD 64  // hidden dim H

// ---------------- init: cnt=1 (self loop), zero accumulators ----------------
__global__ void k_init(int* cnt, float* gacc, float* sE, int N) {
    int i = blockIdx.x * blockDim.x + threadIdx.x;
    if (i < N) cnt[i] = 1;
    if (i < HD) gacc[i] = 0.f;
    if (i < 3) sE[i] = 0.f;
}

// ---------------- u[l][f] = sum_h We_l[f*H+h] * ae_l[h] ----------------
__global__ void k_u(const float* We1, const float* ae1,
                    const float* We2, const float* ae2,
                    const float* We3, const float* ae3,
                    float* u, int FE) {
    int t = threadIdx.x;
    if (t < 3 * FE) {
        int l = t / FE, f = t % FE;
        const float* We = (l == 0) ? We1 : (l == 1) ? We2 : We3;
        const float* ae = (l == 0) ? ae1 : (l == 1) ? ae2 : ae3;
        float s = 0.f;
        for (int hh = 0; hh < HD; ++hh) s += We[f * HD + hh] * ae[hh];
        u[l * FE + f] = s;
    }
}

// ---------------- in-degree histogram over dst ----------------
__global__ void k_hist(const int* __restrict__ ei, int E, int* cnt) {
    int e = blockIdx.x * blockDim.x + threadIdx.x;
    if (e < E) atomicAdd(&cnt[ei[E + e]], 1);
}

// ---------------- single-block exclusive scan -> row_ptr, fill=row_ptr+1 ----------------
__global__ void k_scan(const int* __restrict__ cnt, int* row_ptr, int* fill, int N) {
    const int T = 256;
    __shared__ int sums[T];
    int t = threadIdx.x;
    int per = (N + T - 1) / T;
    int lo = t * per, hi = min(N, lo + per);
    int s = 0;
    for (int i = lo; i < hi; ++i) s += cnt[i];
    sums[t] = s;
    __syncthreads();
    for (int d = 1; d < T; d <<= 1) {
        int v = (t >= d) ? sums[t - d] : 0;
        __syncthreads();
        sums[t] += v;
        __syncthreads();
    }
    int run = sums[t] - s;  // exclusive prefix
    for (int i = lo; i < hi; ++i) {
        row_ptr[i] = run;
        fill[i] = run + 1;  // slot 0 of each segment reserved for the self-loop
        run += cnt[i];
    }
    if (t == T - 1) row_ptr[N] = run;
}

// ---------------- scatter: coalesced LDS-staged alpha dots; ONE float4 record/edge ----------------
// rec[pos] = { src (as int bits), alpha_l1, alpha_l2, alpha_l3 }
__global__ void k_scatter(const int* __restrict__ ei, const float* __restrict__ ea,
                          const float* __restrict__ u, int E, int FE,
                          int* fill, float4* __restrict__ rec, float* sE) {
    extern __shared__ float lds[];
    float* sEA = lds;                      // 256 * (FE+1)
    float* su = lds + 256 * (FE + 1);      // 3 * FE
    int t = threadIdx.x;
    int ldE = FE + 1;

    for (int i = t; i < 3 * FE; i += 256) su[i] = u[i];

    // coalesced float4 staging of this block's 256 edges' attrs
    const float4* ea4 = (const float4*)ea;
    int per_block = 64 * FE;  // 256*FE/4 float4s
    size_t base4 = (size_t)blockIdx.x * per_block;
    size_t tot4 = (size_t)E * FE / 4;
    for (int i = t; i < per_block; i += 256) {
        size_t g4 = base4 + i;
        if (g4 < tot4) {
            float4 v = ea4[g4];
            int g = i * 4;
            int e_loc = g / FE, f = g % FE;
            float* p = &sEA[e_loc * ldE + f];
            p[0] = v.x; p[1] = v.y; p[2] = v.z; p[3] = v.w;
        }
    }
    __syncthreads();

    int e = blockIdx.x * 256 + t;
    float a0 = 0.f, a1 = 0.f, a2 = 0.f;
    bool active = (e < E);
    if (active) {
        const float* row = &sEA[t * ldE];
        for (int f = 0; f < FE; ++f) {
            float v = row[f];
            a0 += v * su[f];
            a1 += v * su[FE + f];
            a2 += v * su[2 * FE + f];
        }
        int src = ei[e], dst = ei[E + e];
        int pos = atomicAdd(&fill[dst], 1);
        rec[pos] = make_float4(__int_as_float(src), a0, a1, a2);
    }
    // wave-reduce alpha sums (for self-loop mean) -> 3 atomics per wave
    float v0 = active ? a0 : 0.f, v1 = active ? a1 : 0.f, v2 = active ? a2 : 0.f;
    for (int d = 32; d; d >>= 1) {
        v0 += __shfl_down(v0, d, 64);
        v1 += __shfl_down(v1, d, 64);
        v2 += __shfl_down(v2, d, 64);
    }
    if ((t & 63) == 0) {
        atomicAdd(&sE[0], v0);
        atomicAdd(&sE[1], v1);
        atomicAdd(&sE[2], v2);
    }
}

// ---------------- fill self-loop record slots ----------------
__global__ void k_self(const int* __restrict__ row_ptr, float4* rec,
                       const float* __restrict__ sE, int N, float invE) {
    int n = blockIdx.x * blockDim.x + threadIdx.x;
    if (n < N) {
        rec[row_ptr[n]] = make_float4(__int_as_float(n), sE[0] * invE,
                                      sE[1] * invE, sE[2] * invE);
    }
}

// ---------------- h = x @ W ; as_n = h.a_s ; ad_n = h.a_d ----------------
__global__ void k_gemm(const float* __restrict__ x, const float* __restrict__ W,
                       const float* __restrict__ a_s, const float* __restrict__ a_d,
                       float* __restrict__ h, float* __restrict__ as_n,
                       float* __restrict__ ad_n, int N, int K) {
    extern __shared__ float lds[];
    float* Ws = lds;            // K*64
    float* Xs = lds + K * HD;   // 16*K
    int t = threadIdx.x;
    int nb = blockIdx.x * 16;
    for (int i = t; i < K * HD; i += 256) Ws[i] = W[i];
    for (int i = t; i < 16 * K; i += 256) {
        int r = i / K, c = i % K;
        int gr = nb + r;
        if (gr >= N) gr = N - 1;
        Xs[i] = x[(size_t)gr * K + c];
    }
    __syncthreads();
    int c = t & 63, w = t >> 6;
    float acc[4] = {0.f, 0.f, 0.f, 0.f};
    for (int k = 0; k < K; ++k) {
        float wv = Ws[k * HD + c];
#pragma unroll
        for (int j = 0; j < 4; ++j) acc[j] += Xs[(w * 4 + j) * K + k] * wv;
    }
    float asv = a_s[c], adv = a_d[c];
#pragma unroll
    for (int j = 0; j < 4; ++j) {
        int n = nb + w * 4 + j;
        if (n >= N) continue;
        h[(size_t)n * HD + c] = acc[j];
        float vs = acc[j] * asv, vd = acc[j] * adv;
        for (int d = 32; d; d >>= 1) {
            vs += __shfl_down(vs, d, 64);
            vd += __shfl_down(vd, d, 64);
        }
        if (c == 0) { as_n[n] = vs; ad_n[n] = vd; }
    }
}

// ---------------- per-node online-softmax aggregation (1 wave per node, 2x unrolled) ----------------
__global__ void k_aggr(const float* __restrict__ h, const float* __restrict__ as_n,
                       const float* __restrict__ ad_n, const int* __restrict__ row_ptr,
                       const float4* __restrict__ rec, int l,
                       const float* __restrict__ b, float* __restrict__ x_out,
                       float* __restrict__ emb, int N, int first) {
    int wave = threadIdx.x >> 6, f = threadIdx.x & 63;
    int n = blockIdx.x * 4 + wave;
    if (n >= N) return;
    int base = row_ptr[n], end = row_ptr[n + 1];
    float adv = ad_n[n];
    float m = -INFINITY, d = 0.f, acc = 0.f;
    int i = base;
    for (; i + 1 < end; i += 2) {
        float4 r0 = rec[i], r1 = rec[i + 1];
        int s0 = __float_as_int(r0.x), s1 = __float_as_int(r1.x);
        float hv0 = h[(size_t)s0 * HD + f];
        float hv1 = h[(size_t)s1 * HD + f];
        float aE0 = (l == 0) ? r0.y : (l == 1) ? r0.z : r0.w;
        float aE1 = (l == 0) ? r1.y : (l == 1) ? r1.z : r1.w;
        float a0 = as_n[s0] + adv + aE0;
        float a1 = as_n[s1] + adv + aE1;
        a0 = (a0 > 0.f) ? a0 : 0.2f * a0;
        a1 = (a1 > 0.f) ? a1 : 0.2f * a1;
        float mn = fmaxf(m, fmaxf(a0, a1));
        float sc = __expf(m - mn);  // first iter: exp(-inf) = 0
        float w0 = __expf(a0 - mn), w1 = __expf(a1 - mn);
        d = d * sc + w0 + w1;
        acc = acc * sc + w0 * hv0 + w1 * hv1;
        m = mn;
    }
    if (i < end) {
        float4 r0 = rec[i];
        int s0 = __float_as_int(r0.x);
        float hv0 = h[(size_t)s0 * HD + f];
        float aE0 = (l == 0) ? r0.y : (l == 1) ? r0.z : r0.w;
        float a0 = as_n[s0] + adv + aE0;
        a0 = (a0 > 0.f) ? a0 : 0.2f * a0;
        float mn = fmaxf(m, a0);
        float sc = __expf(m - mn);
        float w0 = __expf(a0 - mn);
        d = d * sc + w0;
        acc = acc * sc + w0 * hv0;
    }
    float out = acc / (d + 1e-16f) + b[f];
    float v = (out > 0.f) ? out : expm1f(out);
    x_out[(size_t)n * HD + f] = v;
    if (first) emb[(size_t)n * HD + f] = v;
    else emb[(size_t)n * HD + f] += v;
}

// ---------------- column sums of emb -> gacc (atomic) ----------------
__global__ void k_red(const float* __restrict__ emb, float* gacc, int N) {
    __shared__ float lds[256];
    int f = threadIdx.x & 63, w = threadIdx.x >> 6;
    float s = 0.f;
    for (int n = blockIdx.x * 4 + w; n < N; n += gridDim.x * 4)
        s += emb[(size_t)n * HD + f];
    lds[threadIdx.x] = s;
    __syncthreads();
    if (w == 0) {
        float v = lds[f] + lds[64 + f] + lds[128 + f] + lds[192 + f];
        atomicAdd(&gacc[f], v);
    }
}

__global__ void k_div(const float* __restrict__ gacc, float* out, int N) {
    int f = threadIdx.x;
    if (f < HD) out[(size_t)N * HD + f] = gacc[f] / (float)N;
}

extern "C" void kernel_launch(void* const* d_in, const int* in_sizes, int n_in,
                              void* d_out, int out_size, void* d_ws, size_t ws_size,
                              hipStream_t stream) {
    const float* x = (const float*)d_in[0];
    const int* ei = (const int*)d_in[1];
    const float* ea = (const float*)d_in[2];

    const int FIN = in_sizes[3] / HD;       // W1 is [F_IN, 64]
    const int N = in_sizes[0] / FIN;
    const int E = in_sizes[1] / 2;
    const int FE = in_sizes[2] / E;
    const int Ep = E + N;

    const float* W[3];  const float* as_[3]; const float* ad_[3];
    const float* We[3]; const float* ae_[3]; const float* bb[3];
    for (int l = 0; l < 3; ++l) {
        W[l]  = (const float*)d_in[3 + 6 * l + 0];
        as_[l] = (const float*)d_in[3 + 6 * l + 1];
        ad_[l] = (const float*)d_in[3 + 6 * l + 2];
        We[l] = (const float*)d_in[3 + 6 * l + 3];
        ae_[l] = (const float*)d_in[3 + 6 * l + 4];
        bb[l] = (const float*)d_in[3 + 6 * l + 5];
    }

    // ---- workspace layout (bytes, 256-aligned) ----
    char* ws = (char*)d_ws;
    size_t off = 0;
    auto alloc = [&](size_t bytes) {
        void* p = ws + off;
        off += (bytes + 255) & ~(size_t)255;
        return p;
    };
    float*  h      = (float*)alloc((size_t)N * HD * 4);
    float*  x_cur  = (float*)alloc((size_t)N * HD * 4);
    float*  as_n   = (float*)alloc((size_t)N * 4);
    float*  ad_n   = (float*)alloc((size_t)N * 4);
    int*    cnt    = (int*)alloc((size_t)N * 4);
    int*    rowp   = (int*)alloc((size_t)(N + 1) * 4);
    int*    fill   = (int*)alloc((size_t)N * 4);
    float4* rec    = (float4*)alloc((size_t)Ep * 16);
    float*  u      = (float*)alloc((size_t)3 * FE * 4);
    float*  sE     = (float*)alloc(3 * 4);
    float*  gacc   = (float*)alloc(HD * 4);
    (void)ws_size; (void)n_in; (void)out_size;

    float* emb = (float*)d_out;  // [N,64] node embeddings; tail 64 = graph emb

    int gN = (N + 255) / 256;
    int gE = (E + 255) / 256;

    k_init<<<gN, 256, 0, stream>>>(cnt, gacc, sE, N);
    k_u<<<1, 64, 0, stream>>>(We[0], ae_[0], We[1], ae_[1], We[2], ae_[2], u, FE);
    k_hist<<<gE, 256, 0, stream>>>(ei, E, cnt);
    k_scan<<<1, 256, 0, stream>>>(cnt, rowp, fill, N);
    size_t sc_lds = (size_t)(256 * (FE + 1) + 3 * FE) * 4;
    k_scatter<<<gE, 256, sc_lds, stream>>>(ei, ea, u, E, FE, fill, rec, sE);
    k_self<<<gN, 256, 0, stream>>>(rowp, rec, sE, N, 1.0f / (float)E);

    for (int l = 0; l < 3; ++l) {
        const float* xin = (l == 0) ? x : x_cur;
        int K = (l == 0) ? FIN : HD;
        size_t ldsz = (size_t)(K * HD + 16 * K) * 4;
        k_gemm<<<(N + 15) / 16, 256, ldsz, stream>>>(xin, W[l], as_[l], ad_[l],
                                                     h, as_n, ad_n, N, K);
        k_aggr<<<(N + 3) / 4, 256, 0, stream>>>(h, as_n, ad_n, rowp, rec, l,
                                                bb[l], x_cur, emb, N, (l == 0) ? 1 : 0);
    }

    k_red<<<256, 256, 0, stream>>>(emb, gacc, N);
    k_div<<<1, 64, 0, stream>>>(gacc, emb, N);
}

// Round 3
// 663.768 us; speedup vs baseline: 1.7967x; 1.6298x over previous
//
#include <hip/hip_runtime.h>
#include <math.h>

#define HD 64  // hidden dim H

// ---------------- init: cnt=1 (self loop), zero gacc ----------------
__global__ void k_init(int* cnt, float* gacc, int N) {
    int i = blockIdx.x * blockDim.x + threadIdx.x;
    if (i < N) cnt[i] = 1;
    if (i < HD) gacc[i] = 0.f;
}

// ---------------- u[l][f] = sum_h We_l[f*H+h] * ae_l[h] ----------------
__global__ void k_u(const float* We1, const float* ae1,
                    const float* We2, const float* ae2,
                    const float* We3, const float* ae3,
                    float* u, int FE) {
    int t = threadIdx.x;
    if (t < 3 * FE) {
        int l = t / FE, f = t % FE;
        const float* We = (l == 0) ? We1 : (l == 1) ? We2 : We3;
        const float* ae = (l == 0) ? ae1 : (l == 1) ? ae2 : ae3;
        float s = 0.f;
        for (int hh = 0; hh < HD; ++hh) s += We[f * HD + hh] * ae[hh];
        u[l * FE + f] = s;
    }
}

// ---------------- column sums of ea (stage 1): partials[block][FE] ----------------
// assumes FE == 16 (float4 quartets; 256 % 4 == 0 so each thread's quartet is fixed)
__global__ void k_colsum(const float* __restrict__ ea, size_t tot4, float* partials) {
    __shared__ float lds[256 * 4];
    const float4* ea4 = (const float4*)ea;
    int t = threadIdx.x;
    float4 acc = make_float4(0.f, 0.f, 0.f, 0.f);
    for (size_t i = (size_t)blockIdx.x * 256 + t; i < tot4; i += (size_t)gridDim.x * 256) {
        float4 v = ea4[i];
        acc.x += v.x; acc.y += v.y; acc.z += v.z; acc.w += v.w;
    }
    lds[t * 4 + 0] = acc.x; lds[t * 4 + 1] = acc.y;
    lds[t * 4 + 2] = acc.z; lds[t * 4 + 3] = acc.w;
    __syncthreads();
    if (t < 16) {
        int q = t >> 2, j = t & 3;  // feature = q*4 + j ; q = (float4 idx) & 3
        float s = 0.f;
        for (int k = 0; k < 64; ++k) s += lds[(q + k * 4) * 4 + j];
        partials[blockIdx.x * 16 + (q * 4 + j)] = s;
    }
}

// ---------------- stage 2: reduce partials -> mean_ea; sE[l] = mean_ea . u_l ----------------
__global__ void k_u2(const float* __restrict__ partials, int NB,
                     const float* __restrict__ u, float* sE, int FE, float invE) {
    __shared__ float lds[256];
    int t = threadIdx.x;
    int col = t & 15, grp = t >> 4;
    float s = 0.f;
    for (int b = grp; b < NB; b += 16) s += partials[b * FE + col];
    lds[t] = s;
    __syncthreads();
    if (t < 16) {
        float v = 0.f;
        for (int g = 0; g < 16; ++g) v += lds[g * 16 + t];
        lds[t] = v * invE;  // mean_ea[col]
    }
    __syncthreads();
    if (t < 3) {
        float a = 0.f;
        for (int f = 0; f < FE; ++f) a += lds[f] * u[t * FE + f];
        sE[t] = a;  // self-loop alpha_e for layer t
    }
}

// ---------------- in-degree histogram over dst ----------------
__global__ void k_hist(const int* __restrict__ ei, int E, int* cnt) {
    int e = blockIdx.x * blockDim.x + threadIdx.x;
    if (e < E) atomicAdd(&cnt[ei[E + e]], 1);
}

// ---------------- single-block exclusive scan -> row_ptr, fill=row_ptr+1 ----------------
__global__ void k_scan(const int* __restrict__ cnt, int* row_ptr, int* fill, int N) {
    const int T = 256;
    __shared__ int sums[T];
    int t = threadIdx.x;
    int per = (N + T - 1) / T;
    int lo = t * per, hi = min(N, lo + per);
    int s = 0;
    for (int i = lo; i < hi; ++i) s += cnt[i];
    sums[t] = s;
    __syncthreads();
    for (int d = 1; d < T; d <<= 1) {
        int v = (t >= d) ? sums[t - d] : 0;
        __syncthreads();
        sums[t] += v;
        __syncthreads();
    }
    int run = sums[t] - s;  // exclusive prefix
    for (int i = lo; i < hi; ++i) {
        row_ptr[i] = run;
        fill[i] = run + 1;  // slot 0 of each segment reserved for the self-loop
        run += cnt[i];
    }
    if (t == T - 1) row_ptr[N] = run;
}

// ---------------- scatter: LDS-staged alpha dots; ONE float4 record/edge; NO hot atomics ----------------
// rec[pos] = { src (as int bits), alpha_l1, alpha_l2, alpha_l3 }
__global__ void k_scatter(const int* __restrict__ ei, const float* __restrict__ ea,
                          const float* __restrict__ u, int E, int FE,
                          int* fill, float4* __restrict__ rec) {
    extern __shared__ float lds[];
    float* sEA = lds;                      // 256 * (FE+1)
    float* su = lds + 256 * (FE + 1);      // 3 * FE
    int t = threadIdx.x;
    int ldE = FE + 1;

    for (int i = t; i < 3 * FE; i += 256) su[i] = u[i];

    // coalesced float4 staging of this block's 256 edges' attrs
    const float4* ea4 = (const float4*)ea;
    int per_block = 64 * FE;  // 256*FE/4 float4s
    size_t base4 = (size_t)blockIdx.x * per_block;
    size_t tot4 = (size_t)E * FE / 4;
    for (int i = t; i < per_block; i += 256) {
        size_t g4 = base4 + i;
        if (g4 < tot4) {
            float4 v = ea4[g4];
            int g = i * 4;
            int e_loc = g / FE, f = g % FE;
            float* p = &sEA[e_loc * ldE + f];
            p[0] = v.x; p[1] = v.y; p[2] = v.z; p[3] = v.w;
        }
    }
    __syncthreads();

    int e = blockIdx.x * 256 + t;
    if (e < E) {
        float a0 = 0.f, a1 = 0.f, a2 = 0.f;
        const float* row = &sEA[t * ldE];
        for (int f = 0; f < FE; ++f) {
            float v = row[f];
            a0 += v * su[f];
            a1 += v * su[FE + f];
            a2 += v * su[2 * FE + f];
        }
        int src = ei[e], dst = ei[E + e];
        int pos = atomicAdd(&fill[dst], 1);
        rec[pos] = make_float4(__int_as_float(src), a0, a1, a2);
    }
}

// ---------------- fill self-loop record slots ----------------
__global__ void k_self(const int* __restrict__ row_ptr, float4* rec,
                       const float* __restrict__ sE, int N) {
    int n = blockIdx.x * blockDim.x + threadIdx.x;
    if (n < N) {
        rec[row_ptr[n]] = make_float4(__int_as_float(n), sE[0], sE[1], sE[2]);
    }
}

// ---------------- h = x @ W ; as_n = h.a_s ; ad_n = h.a_d ----------------
__global__ void k_gemm(const float* __restrict__ x, const float* __restrict__ W,
                       const float* __restrict__ a_s, const float* __restrict__ a_d,
                       float* __restrict__ h, float* __restrict__ as_n,
                       float* __restrict__ ad_n, int N, int K) {
    extern __shared__ float lds[];
    float* Ws = lds;            // K*64
    float* Xs = lds + K * HD;   // 16*K
    int t = threadIdx.x;
    int nb = blockIdx.x * 16;
    for (int i = t; i < K * HD; i += 256) Ws[i] = W[i];
    for (int i = t; i < 16 * K; i += 256) {
        int r = i / K, c = i % K;
        int gr = nb + r;
        if (gr >= N) gr = N - 1;
        Xs[i] = x[(size_t)gr * K + c];
    }
    __syncthreads();
    int c = t & 63, w = t >> 6;
    float acc[4] = {0.f, 0.f, 0.f, 0.f};
    for (int k = 0; k < K; ++k) {
        float wv = Ws[k * HD + c];
#pragma unroll
        for (int j = 0; j < 4; ++j) acc[j] += Xs[(w * 4 + j) * K + k] * wv;
    }
    float asv = a_s[c], adv = a_d[c];
#pragma unroll
    for (int j = 0; j < 4; ++j) {
        int n = nb + w * 4 + j;
        if (n >= N) continue;
        h[(size_t)n * HD + c] = acc[j];
        float vs = acc[j] * asv, vd = acc[j] * adv;
        for (int d = 32; d; d >>= 1) {
            vs += __shfl_down(vs, d, 64);
            vd += __shfl_down(vd, d, 64);
        }
        if (c == 0) { as_n[n] = vs; ad_n[n] = vd; }
    }
}

// ---------------- per-node online-softmax aggregation (1 wave per node, 2x unrolled) ----------------
__global__ void k_aggr(const float* __restrict__ h, const float* __restrict__ as_n,
                       const float* __restrict__ ad_n, const int* __restrict__ row_ptr,
                       const float4* __restrict__ rec, int l,
                       const float* __restrict__ b, float* __restrict__ x_out,
                       float* __restrict__ emb, int N, int first) {
    int wave = threadIdx.x >> 6, f = threadIdx.x & 63;
    int n = blockIdx.x * 4 + wave;
    if (n >= N) return;
    int base = row_ptr[n], end = row_ptr[n + 1];
    float adv = ad_n[n];
    float m = -INFINITY, d = 0.f, acc = 0.f;
    int i = base;
    for (; i + 1 < end; i += 2) {
        float4 r0 = rec[i], r1 = rec[i + 1];
        int s0 = __float_as_int(r0.x), s1 = __float_as_int(r1.x);
        float hv0 = h[(size_t)s0 * HD + f];
        float hv1 = h[(size_t)s1 * HD + f];
        float aE0 = (l == 0) ? r0.y : (l == 1) ? r0.z : r0.w;
        float aE1 = (l == 0) ? r1.y : (l == 1) ? r1.z : r1.w;
        float a0 = as_n[s0] + adv + aE0;
        float a1 = as_n[s1] + adv + aE1;
        a0 = (a0 > 0.f) ? a0 : 0.2f * a0;
        a1 = (a1 > 0.f) ? a1 : 0.2f * a1;
        float mn = fmaxf(m, fmaxf(a0, a1));
        float sc = __expf(m - mn);  // first iter: exp(-inf) = 0
        float w0 = __expf(a0 - mn), w1 = __expf(a1 - mn);
        d = d * sc + w0 + w1;
        acc = acc * sc + w0 * hv0 + w1 * hv1;
        m = mn;
    }
    if (i < end) {
        float4 r0 = rec[i];
        int s0 = __float_as_int(r0.x);
        float hv0 = h[(size_t)s0 * HD + f];
        float aE0 = (l == 0) ? r0.y : (l == 1) ? r0.z : r0.w;
        float a0 = as_n[s0] + adv + aE0;
        a0 = (a0 > 0.f) ? a0 : 0.2f * a0;
        float mn = fmaxf(m, a0);
        float sc = __expf(m - mn);
        float w0 = __expf(a0 - mn);
        d = d * sc + w0;
        acc = acc * sc + w0 * hv0;
    }
    float out = acc / (d + 1e-16f) + b[f];
    float v = (out > 0.f) ? out : expm1f(out);
    x_out[(size_t)n * HD + f] = v;
    if (first) emb[(size_t)n * HD + f] = v;
    else emb[(size_t)n * HD + f] += v;
}

// ---------------- column sums of emb -> gacc (atomic) ----------------
__global__ void k_red(const float* __restrict__ emb, float* gacc, int N) {
    __shared__ float lds[256];
    int f = threadIdx.x & 63, w = threadIdx.x >> 6;
    float s = 0.f;
    for (int n = blockIdx.x * 4 + w; n < N; n += gridDim.x * 4)
        s += emb[(size_t)n * HD + f];
    lds[threadIdx.x] = s;
    __syncthreads();
    if (w == 0) {
        float v = lds[f] + lds[64 + f] + lds[128 + f] + lds[192 + f];
        atomicAdd(&gacc[f], v);
    }
}

__global__ void k_div(const float* __restrict__ gacc, float* out, int N) {
    int f = threadIdx.x;
    if (f < HD) out[(size_t)N * HD + f] = gacc[f] / (float)N;
}

extern "C" void kernel_launch(void* const* d_in, const int* in_sizes, int n_in,
                              void* d_out, int out_size, void* d_ws, size_t ws_size,
                              hipStream_t stream) {
    const float* x = (const float*)d_in[0];
    const int* ei = (const int*)d_in[1];
    const float* ea = (const float*)d_in[2];

    const int FIN = in_sizes[3] / HD;       // W1 is [F_IN, 64]
    const int N = in_sizes[0] / FIN;
    const int E = in_sizes[1] / 2;
    const int FE = in_sizes[2] / E;
    const int Ep = E + N;
    const int NB = 1024;                    // colsum partial blocks

    const float* W[3];  const float* as_[3]; const float* ad_[3];
    const float* We[3]; const float* ae_[3]; const float* bb[3];
    for (int l = 0; l < 3; ++l) {
        W[l]  = (const float*)d_in[3 + 6 * l + 0];
        as_[l] = (const float*)d_in[3 + 6 * l + 1];
        ad_[l] = (const float*)d_in[3 + 6 * l + 2];
        We[l] = (const float*)d_in[3 + 6 * l + 3];
        ae_[l] = (const float*)d_in[3 + 6 * l + 4];
        bb[l] = (const float*)d_in[3 + 6 * l + 5];
    }

    // ---- workspace layout (bytes, 256-aligned) ----
    char* ws = (char*)d_ws;
    size_t off = 0;
    auto alloc = [&](size_t bytes) {
        void* p = ws + off;
        off += (bytes + 255) & ~(size_t)255;
        return p;
    };
    float*  h      = (float*)alloc((size_t)N * HD * 4);
    float*  x_cur  = (float*)alloc((size_t)N * HD * 4);
    float*  as_n   = (float*)alloc((size_t)N * 4);
    float*  ad_n   = (float*)alloc((size_t)N * 4);
    int*    cnt    = (int*)alloc((size_t)N * 4);
    int*    rowp   = (int*)alloc((size_t)(N + 1) * 4);
    int*    fill   = (int*)alloc((size_t)N * 4);
    float4* rec    = (float4*)alloc((size_t)Ep * 16);
    float*  u      = (float*)alloc((size_t)3 * FE * 4);
    float*  partials = (float*)alloc((size_t)NB * FE * 4);
    float*  sE     = (float*)alloc(3 * 4);
    float*  gacc   = (float*)alloc(HD * 4);
    (void)ws_size; (void)n_in; (void)out_size;

    float* emb = (float*)d_out;  // [N,64] node embeddings; tail 64 = graph emb

    int gN = (N + 255) / 256;
    int gE = (E + 255) / 256;
    size_t tot4 = (size_t)E * FE / 4;

    k_init<<<gN, 256, 0, stream>>>(cnt, gacc, N);
    k_u<<<1, 64, 0, stream>>>(We[0], ae_[0], We[1], ae_[1], We[2], ae_[2], u, FE);
    k_colsum<<<NB, 256, 0, stream>>>(ea, tot4, partials);
    k_u2<<<1, 256, 0, stream>>>(partials, NB, u, sE, FE, 1.0f / (float)E);
    k_hist<<<gE, 256, 0, stream>>>(ei, E, cnt);
    k_scan<<<1, 256, 0, stream>>>(cnt, rowp, fill, N);
    size_t sc_lds = (size_t)(256 * (FE + 1) + 3 * FE) * 4;
    k_scatter<<<gE, 256, sc_lds, stream>>>(ei, ea, u, E, FE, fill, rec);
    k_self<<<gN, 256, 0, stream>>>(rowp, rec, sE, N);

    for (int l = 0; l < 3; ++l) {
        const float* xin = (l == 0) ? x : x_cur;
        int K = (l == 0) ? FIN : HD;
        size_t ldsz = (size_t)(K * HD + 16 * K) * 4;
        k_gemm<<<(N + 15) / 16, 256, ldsz, stream>>>(xin, W[l], as_[l], ad_[l],
                                                     h, as_n, ad_n, N, K);
        k_aggr<<<(N + 3) / 4, 256, 0, stream>>>(h, as_n, ad_n, rowp, rec, l,
                                                bb[l], x_cur, emb, N, (l == 0) ? 1 : 0);
    }

    k_red<<<256, 256, 0, stream>>>(emb, gacc, N);
    k_div<<<1, 64, 0, stream>>>(gacc, emb, N);
}

// Round 4
// 560.947 us; speedup vs baseline: 2.1260x; 1.1833x over previous
//
#include <hip/hip_runtime.h>
#include <math.h>

#define HD 64  // hidden dim H

// ---------------- init: cnt=1 (self loop), zero gacc ----------------
__global__ void k_init(int* cnt, float* gacc, int N) {
    int i = blockIdx.x * blockDim.x + threadIdx.x;
    if (i < N) cnt[i] = 1;
    if (i < HD) gacc[i] = 0.f;
}

// ---------------- u[l][f] = sum_h We_l[f*H+h] * ae_l[h] ----------------
__global__ void k_u(const float* We1, const float* ae1,
                    const float* We2, const float* ae2,
                    const float* We3, const float* ae3,
                    float* u, int FE) {
    int t = threadIdx.x;
    if (t < 3 * FE) {
        int l = t / FE, f = t % FE;
        const float* We = (l == 0) ? We1 : (l == 1) ? We2 : We3;
        const float* ae = (l == 0) ? ae1 : (l == 1) ? ae2 : ae3;
        float s = 0.f;
        for (int hh = 0; hh < HD; ++hh) s += We[f * HD + hh] * ae[hh];
        u[l * FE + f] = s;
    }
}

// ---------------- column sums of ea (stage 1): partials[block][FE] ----------------
// assumes FE == 16 (float4 quartets; 256 % 4 == 0 so each thread's quartet is fixed)
__global__ void k_colsum(const float* __restrict__ ea, size_t tot4, float* partials) {
    __shared__ float lds[256 * 4];
    const float4* ea4 = (const float4*)ea;
    int t = threadIdx.x;
    float4 acc = make_float4(0.f, 0.f, 0.f, 0.f);
    for (size_t i = (size_t)blockIdx.x * 256 + t; i < tot4; i += (size_t)gridDim.x * 256) {
        float4 v = ea4[i];
        acc.x += v.x; acc.y += v.y; acc.z += v.z; acc.w += v.w;
    }
    lds[t * 4 + 0] = acc.x; lds[t * 4 + 1] = acc.y;
    lds[t * 4 + 2] = acc.z; lds[t * 4 + 3] = acc.w;
    __syncthreads();
    if (t < 16) {
        int q = t >> 2, j = t & 3;  // feature = q*4 + j ; q = (float4 idx) & 3
        float s = 0.f;
        for (int k = 0; k < 64; ++k) s += lds[(q + k * 4) * 4 + j];
        partials[blockIdx.x * 16 + (q * 4 + j)] = s;
    }
}

// ---------------- stage 2: reduce partials -> mean_ea; sE[l] = mean_ea . u_l ----------------
__global__ void k_u2(const float* __restrict__ partials, int NB,
                     const float* __restrict__ u, float* sE, int FE, float invE) {
    __shared__ float lds[256];
    int t = threadIdx.x;
    int col = t & 15, grp = t >> 4;
    float s = 0.f;
    for (int b = grp; b < NB; b += 16) s += partials[b * FE + col];
    lds[t] = s;
    __syncthreads();
    if (t < 16) {
        float v = 0.f;
        for (int g = 0; g < 16; ++g) v += lds[g * 16 + t];
        lds[t] = v * invE;  // mean_ea[col]
    }
    __syncthreads();
    if (t < 3) {
        float a = 0.f;
        for (int f = 0; f < FE; ++f) a += lds[f] * u[t * FE + f];
        sE[t] = a;  // self-loop alpha_e for layer t
    }
}

// ---------------- in-degree histogram over dst ----------------
__global__ void k_hist(const int* __restrict__ ei, int E, int* cnt) {
    int e = blockIdx.x * blockDim.x + threadIdx.x;
    if (e < E) atomicAdd(&cnt[ei[E + e]], 1);
}

// ---------------- 3-stage parallel exclusive scan over cnt ----------------
// A: per-block Hillis-Steele, per-node exclusive prefix + block sums
__global__ void k_scanA(const int* __restrict__ cnt, int* pre, int* blocksums, int N) {
    __shared__ int lds[256];
    int t = threadIdx.x;
    int n = blockIdx.x * 256 + t;
    int v = (n < N) ? cnt[n] : 0;
    lds[t] = v;
    __syncthreads();
    for (int d = 1; d < 256; d <<= 1) {
        int x = (t >= d) ? lds[t - d] : 0;
        __syncthreads();
        lds[t] += x;
        __syncthreads();
    }
    if (n < N) pre[n] = lds[t] - v;  // exclusive within block
    if (t == 255) blocksums[blockIdx.x] = lds[255];
}

// B: single-block scan of block sums (NBLK <= 256)
__global__ void k_scanB(int* blocksums, int NBLK, int* total) {
    __shared__ int lds[256];
    int t = threadIdx.x;
    int v = (t < NBLK) ? blocksums[t] : 0;
    lds[t] = v;
    __syncthreads();
    for (int d = 1; d < 256; d <<= 1) {
        int x = (t >= d) ? lds[t - d] : 0;
        __syncthreads();
        lds[t] += x;
        __syncthreads();
    }
    if (t < NBLK) blocksums[t] = lds[t] - v;  // exclusive block offsets
    if (t == 255) *total = lds[255];
}

// C: combine -> row_ptr, fill = row_ptr + 1 (self-loop slot reserved)
__global__ void k_scanC(const int* __restrict__ pre, const int* __restrict__ blocksums,
                        const int* __restrict__ total, int* row_ptr, int* fill, int N) {
    int n = blockIdx.x * 256 + threadIdx.x;
    if (n < N) {
        int r = pre[n] + blocksums[blockIdx.x];
        row_ptr[n] = r;
        fill[n] = r + 1;
    }
    if (n == 0) row_ptr[N] = *total;
}

// ---------------- scatter: LDS-staged alpha dots; ONE float4 record/edge ----------------
// rec[pos] = { src (as int bits), alpha_l1, alpha_l2, alpha_l3 }
__global__ void k_scatter(const int* __restrict__ ei, const float* __restrict__ ea,
                          const float* __restrict__ u, int E, int FE,
                          int* fill, float4* __restrict__ rec) {
    extern __shared__ float lds[];
    float* sEA = lds;                      // 256 * (FE+1)
    float* su = lds + 256 * (FE + 1);      // 3 * FE
    int t = threadIdx.x;
    int ldE = FE + 1;

    for (int i = t; i < 3 * FE; i += 256) su[i] = u[i];

    // coalesced float4 staging of this block's 256 edges' attrs
    const float4* ea4 = (const float4*)ea;
    int per_block = 64 * FE;  // 256*FE/4 float4s
    size_t base4 = (size_t)blockIdx.x * per_block;
    size_t tot4 = (size_t)E * FE / 4;
    for (int i = t; i < per_block; i += 256) {
        size_t g4 = base4 + i;
        if (g4 < tot4) {
            float4 v = ea4[g4];
            int g = i * 4;
            int e_loc = g / FE, f = g % FE;
            float* p = &sEA[e_loc * ldE + f];
            p[0] = v.x; p[1] = v.y; p[2] = v.z; p[3] = v.w;
        }
    }
    __syncthreads();

    int e = blockIdx.x * 256 + t;
    if (e < E) {
        float a0 = 0.f, a1 = 0.f, a2 = 0.f;
        const float* row = &sEA[t * ldE];
        for (int f = 0; f < FE; ++f) {
            float v = row[f];
            a0 += v * su[f];
            a1 += v * su[FE + f];
            a2 += v * su[2 * FE + f];
        }
        int src = ei[e], dst = ei[E + e];
        int pos = atomicAdd(&fill[dst], 1);
        rec[pos] = make_float4(__int_as_float(src), a0, a1, a2);
    }
}

// ---------------- fill self-loop record slots ----------------
__global__ void k_self(const int* __restrict__ row_ptr, float4* rec,
                       const float* __restrict__ sE, int N) {
    int n = blockIdx.x * blockDim.x + threadIdx.x;
    if (n < N) {
        rec[row_ptr[n]] = make_float4(__int_as_float(n), sE[0], sE[1], sE[2]);
    }
}

// ---------------- h = x @ W ; as_n = h.a_s ; ad_n = h.a_d ----------------
__global__ void k_gemm(const float* __restrict__ x, const float* __restrict__ W,
                       const float* __restrict__ a_s, const float* __restrict__ a_d,
                       float* __restrict__ h, float* __restrict__ as_n,
                       float* __restrict__ ad_n, int N, int K) {
    extern __shared__ float lds[];
    float* Ws = lds;            // K*64
    float* Xs = lds + K * HD;   // 16*K
    int t = threadIdx.x;
    int nb = blockIdx.x * 16;
    for (int i = t; i < K * HD; i += 256) Ws[i] = W[i];
    for (int i = t; i < 16 * K; i += 256) {
        int r = i / K, c = i % K;
        int gr = nb + r;
        if (gr >= N) gr = N - 1;
        Xs[i] = x[(size_t)gr * K + c];
    }
    __syncthreads();
    int c = t & 63, w = t >> 6;
    float acc[4] = {0.f, 0.f, 0.f, 0.f};
    for (int k = 0; k < K; ++k) {
        float wv = Ws[k * HD + c];
#pragma unroll
        for (int j = 0; j < 4; ++j) acc[j] += Xs[(w * 4 + j) * K + k] * wv;
    }
    float asv = a_s[c], adv = a_d[c];
#pragma unroll
    for (int j = 0; j < 4; ++j) {
        int n = nb + w * 4 + j;
        if (n >= N) continue;
        h[(size_t)n * HD + c] = acc[j];
        float vs = acc[j] * asv, vd = acc[j] * adv;
        for (int d = 32; d; d >>= 1) {
            vs += __shfl_down(vs, d, 64);
            vd += __shfl_down(vd, d, 64);
        }
        if (c == 0) { as_n[n] = vs; ad_n[n] = vd; }
    }
}

// ---------------- per-node online-softmax aggregation (1 wave per node, 2x unrolled) ----------------
__global__ void k_aggr(const float* __restrict__ h, const float* __restrict__ as_n,
                       const float* __restrict__ ad_n, const int* __restrict__ row_ptr,
                       const float4* __restrict__ rec, int l,
                       const float* __restrict__ b, float* __restrict__ x_out,
                       float* __restrict__ emb, int N, int first) {
    int wave = threadIdx.x >> 6, f = threadIdx.x & 63;
    int n = blockIdx.x * 4 + wave;
    if (n >= N) return;
    int base = row_ptr[n], end = row_ptr[n + 1];
    float adv = ad_n[n];
    float m = -INFINITY, d = 0.f, acc = 0.f;
    int i = base;
    for (; i + 1 < end; i += 2) {
        float4 r0 = rec[i], r1 = rec[i + 1];
        int s0 = __float_as_int(r0.x), s1 = __float_as_int(r1.x);
        float hv0 = h[(size_t)s0 * HD + f];
        float hv1 = h[(size_t)s1 * HD + f];
        float aE0 = (l == 0) ? r0.y : (l == 1) ? r0.z : r0.w;
        float aE1 = (l == 0) ? r1.y : (l == 1) ? r1.z : r1.w;
        float a0 = as_n[s0] + adv + aE0;
        float a1 = as_n[s1] + adv + aE1;
        a0 = (a0 > 0.f) ? a0 : 0.2f * a0;
        a1 = (a1 > 0.f) ? a1 : 0.2f * a1;
        float mn = fmaxf(m, fmaxf(a0, a1));
        float sc = __expf(m - mn);  // first iter: exp(-inf) = 0
        float w0 = __expf(a0 - mn), w1 = __expf(a1 - mn);
        d = d * sc + w0 + w1;
        acc = acc * sc + w0 * hv0 + w1 * hv1;
        m = mn;
    }
    if (i < end) {
        float4 r0 = rec[i];
        int s0 = __float_as_int(r0.x);
        float hv0 = h[(size_t)s0 * HD + f];
        float aE0 = (l == 0) ? r0.y : (l == 1) ? r0.z : r0.w;
        float a0 = as_n[s0] + adv + aE0;
        a0 = (a0 > 0.f) ? a0 : 0.2f * a0;
        float mn = fmaxf(m, a0);
        float sc = __expf(m - mn);
        float w0 = __expf(a0 - mn);
        d = d * sc + w0;
        acc = acc * sc + w0 * hv0;
    }
    float out = acc / (d + 1e-16f) + b[f];
    float v = (out > 0.f) ? out : expm1f(out);
    x_out[(size_t)n * HD + f] = v;
    if (first) emb[(size_t)n * HD + f] = v;
    else emb[(size_t)n * HD + f] += v;
}

// ---------------- column sums of emb -> gacc (atomic) ----------------
__global__ void k_red(const float* __restrict__ emb, float* gacc, int N) {
    __shared__ float lds[256];
    int f = threadIdx.x & 63, w = threadIdx.x >> 6;
    float s = 0.f;
    for (int n = blockIdx.x * 4 + w; n < N; n += gridDim.x * 4)
        s += emb[(size_t)n * HD + f];
    lds[threadIdx.x] = s;
    __syncthreads();
    if (w == 0) {
        float v = lds[f] + lds[64 + f] + lds[128 + f] + lds[192 + f];
        atomicAdd(&gacc[f], v);
    }
}

__global__ void k_div(const float* __restrict__ gacc, float* out, int N) {
    int f = threadIdx.x;
    if (f < HD) out[(size_t)N * HD + f] = gacc[f] / (float)N;
}

extern "C" void kernel_launch(void* const* d_in, const int* in_sizes, int n_in,
                              void* d_out, int out_size, void* d_ws, size_t ws_size,
                              hipStream_t stream) {
    const float* x = (const float*)d_in[0];
    const int* ei = (const int*)d_in[1];
    const float* ea = (const float*)d_in[2];

    const int FIN = in_sizes[3] / HD;       // W1 is [F_IN, 64]
    const int N = in_sizes[0] / FIN;
    const int E = in_sizes[1] / 2;
    const int FE = in_sizes[2] / E;
    const int Ep = E + N;
    const int NB = 1024;                    // colsum partial blocks

    const float* W[3];  const float* as_[3]; const float* ad_[3];
    const float* We[3]; const float* ae_[3]; const float* bb[3];
    for (int l = 0; l < 3; ++l) {
        W[l]  = (const float*)d_in[3 + 6 * l + 0];
        as_[l] = (const float*)d_in[3 + 6 * l + 1];
        ad_[l] = (const float*)d_in[3 + 6 * l + 2];
        We[l] = (const float*)d_in[3 + 6 * l + 3];
        ae_[l] = (const float*)d_in[3 + 6 * l + 4];
        bb[l] = (const float*)d_in[3 + 6 * l + 5];
    }

    // ---- workspace layout (bytes, 256-aligned) ----
    char* ws = (char*)d_ws;
    size_t off = 0;
    auto alloc = [&](size_t bytes) {
        void* p = ws + off;
        off += (bytes + 255) & ~(size_t)255;
        return p;
    };
    float*  h      = (float*)alloc((size_t)N * HD * 4);
    float*  x_cur  = (float*)alloc((size_t)N * HD * 4);
    float*  as_n   = (float*)alloc((size_t)N * 4);
    float*  ad_n   = (float*)alloc((size_t)N * 4);
    int*    cnt    = (int*)alloc((size_t)N * 4);
    int*    rowp   = (int*)alloc((size_t)(N + 1) * 4);
    int*    fill   = (int*)alloc((size_t)N * 4);
    int*    pre    = (int*)alloc((size_t)N * 4);
    int*    bsums  = (int*)alloc(256 * 4);
    int*    total  = (int*)alloc(4);
    float4* rec    = (float4*)alloc((size_t)Ep * 16);
    float*  u      = (float*)alloc((size_t)3 * FE * 4);
    float*  partials = (float*)alloc((size_t)NB * FE * 4);
    float*  sE     = (float*)alloc(3 * 4);
    float*  gacc   = (float*)alloc(HD * 4);
    (void)ws_size; (void)n_in; (void)out_size;

    float* emb = (float*)d_out;  // [N,64] node embeddings; tail 64 = graph emb

    int gN = (N + 255) / 256;
    int gE = (E + 255) / 256;
    size_t tot4 = (size_t)E * FE / 4;

    k_init<<<gN, 256, 0, stream>>>(cnt, gacc, N);
    k_u<<<1, 64, 0, stream>>>(We[0], ae_[0], We[1], ae_[1], We[2], ae_[2], u, FE);
    k_colsum<<<NB, 256, 0, stream>>>(ea, tot4, partials);
    k_u2<<<1, 256, 0, stream>>>(partials, NB, u, sE, FE, 1.0f / (float)E);
    k_hist<<<gE, 256, 0, stream>>>(ei, E, cnt);
    k_scanA<<<gN, 256, 0, stream>>>(cnt, pre, bsums, N);
    k_scanB<<<1, 256, 0, stream>>>(bsums, gN, total);
    k_scanC<<<gN, 256, 0, stream>>>(pre, bsums, total, rowp, fill, N);
    size_t sc_lds = (size_t)(256 * (FE + 1) + 3 * FE) * 4;
    k_scatter<<<gE, 256, sc_lds, stream>>>(ei, ea, u, E, FE, fill, rec);
    k_self<<<gN, 256, 0, stream>>>(rowp, rec, sE, N);

    for (int l = 0; l < 3; ++l) {
        const float* xin = (l == 0) ? x : x_cur;
        int K = (l == 0) ? FIN : HD;
        size_t ldsz = (size_t)(K * HD + 16 * K) * 4;
        k_gemm<<<(N + 15) / 16, 256, ldsz, stream>>>(xin, W[l], as_[l], ad_[l],
                                                     h, as_n, ad_n, N, K);
        k_aggr<<<(N + 3) / 4, 256, 0, stream>>>(h, as_n, ad_n, rowp, rec, l,
                                                bb[l], x_cur, emb, N, (l == 0) ? 1 : 0);
    }

    k_red<<<256, 256, 0, stream>>>(emb, gacc, N);
    k_div<<<1, 64, 0, stream>>>(gacc, emb, N);
}

// Round 5
// 504.215 us; speedup vs baseline: 2.3652x; 1.1125x over previous
//
#include <hip/hip_runtime.h>
#include <math.h>

#define HD 64  // hidden dim H

// ---------------- init: cnt=1 (self loop), zero gacc ----------------
__global__ void k_init(int* cnt, float* gacc, int N) {
    int i = blockIdx.x * blockDim.x + threadIdx.x;
    if (i < N) cnt[i] = 1;
    if (i < HD) gacc[i] = 0.f;
}

// ---------------- u[l][f] = sum_h We_l[f*H+h] * ae_l[h] ----------------
__global__ void k_u(const float* We1, const float* ae1,
                    const float* We2, const float* ae2,
                    const float* We3, const float* ae3,
                    float* u, int FE) {
    int t = threadIdx.x;
    if (t < 3 * FE) {
        int l = t / FE, f = t % FE;
        const float* We = (l == 0) ? We1 : (l == 1) ? We2 : We3;
        const float* ae = (l == 0) ? ae1 : (l == 1) ? ae2 : ae3;
        float s = 0.f;
        for (int hh = 0; hh < HD; ++hh) s += We[f * HD + hh] * ae[hh];
        u[l * FE + f] = s;
    }
}

// ---------------- column sums of ea (stage 1): partials[block][FE] ----------------
__global__ void k_colsum(const float* __restrict__ ea, size_t tot4, float* partials) {
    __shared__ float lds[256 * 4];
    const float4* ea4 = (const float4*)ea;
    int t = threadIdx.x;
    float4 acc = make_float4(0.f, 0.f, 0.f, 0.f);
    for (size_t i = (size_t)blockIdx.x * 256 + t; i < tot4; i += (size_t)gridDim.x * 256) {
        float4 v = ea4[i];
        acc.x += v.x; acc.y += v.y; acc.z += v.z; acc.w += v.w;
    }
    lds[t * 4 + 0] = acc.x; lds[t * 4 + 1] = acc.y;
    lds[t * 4 + 2] = acc.z; lds[t * 4 + 3] = acc.w;
    __syncthreads();
    if (t < 16) {
        int q = t >> 2, j = t & 3;  // feature = q*4 + j
        float s = 0.f;
        for (int k = 0; k < 64; ++k) s += lds[(q + k * 4) * 4 + j];
        partials[blockIdx.x * 16 + (q * 4 + j)] = s;
    }
}

// ---------------- stage 2: reduce partials -> mean_ea; sE[l] = mean_ea . u_l ----------------
__global__ void k_u2(const float* __restrict__ partials, int NB,
                     const float* __restrict__ u, float* sE, int FE, float invE) {
    __shared__ float lds[256];
    int t = threadIdx.x;
    int col = t & 15, grp = t >> 4;
    float s = 0.f;
    for (int b = grp; b < NB; b += 16) s += partials[b * FE + col];
    lds[t] = s;
    __syncthreads();
    if (t < 16) {
        float v = 0.f;
        for (int g = 0; g < 16; ++g) v += lds[g * 16 + t];
        lds[t] = v * invE;  // mean_ea[col]
    }
    __syncthreads();
    if (t < 3) {
        float a = 0.f;
        for (int f = 0; f < FE; ++f) a += lds[f] * u[t * FE + f];
        sE[t] = a;  // self-loop alpha_e for layer t
    }
}

// ---------------- in-degree histogram over dst ----------------
__global__ void k_hist(const int* __restrict__ ei, int E, int* cnt) {
    int e = blockIdx.x * blockDim.x + threadIdx.x;
    if (e < E) atomicAdd(&cnt[ei[E + e]], 1);
}

// ---------------- 3-stage parallel exclusive scan over cnt ----------------
__global__ void k_scanA(const int* __restrict__ cnt, int* pre, int* blocksums, int N) {
    __shared__ int lds[256];
    int t = threadIdx.x;
    int n = blockIdx.x * 256 + t;
    int v = (n < N) ? cnt[n] : 0;
    lds[t] = v;
    __syncthreads();
    for (int d = 1; d < 256; d <<= 1) {
        int x = (t >= d) ? lds[t - d] : 0;
        __syncthreads();
        lds[t] += x;
        __syncthreads();
    }
    if (n < N) pre[n] = lds[t] - v;  // exclusive within block
    if (t == 255) blocksums[blockIdx.x] = lds[255];
}

__global__ void k_scanB(int* blocksums, int NBLK, int* total) {
    __shared__ int lds[256];
    int t = threadIdx.x;
    int v = (t < NBLK) ? blocksums[t] : 0;
    lds[t] = v;
    __syncthreads();
    for (int d = 1; d < 256; d <<= 1) {
        int x = (t >= d) ? lds[t - d] : 0;
        __syncthreads();
        lds[t] += x;
        __syncthreads();
    }
    if (t < NBLK) blocksums[t] = lds[t] - v;  // exclusive block offsets
    if (t == 255) *total = lds[255];
}

__global__ void k_scanC(const int* __restrict__ pre, const int* __restrict__ blocksums,
                        const int* __restrict__ total, int* row_ptr, int* fill, int N) {
    int n = blockIdx.x * 256 + threadIdx.x;
    if (n < N) {
        int r = pre[n] + blocksums[blockIdx.x];
        row_ptr[n] = r;
        fill[n] = r + 1;
    }
    if (n == 0) row_ptr[N] = *total;
}

// ---------------- scatter: LDS-staged alpha dots; ONE float4 record/edge ----------------
// rec[pos] = { src (as int bits), alpha_l1, alpha_l2, alpha_l3 }
__global__ void k_scatter(const int* __restrict__ ei, const float* __restrict__ ea,
                          const float* __restrict__ u, int E, int FE,
                          int* fill, float4* __restrict__ rec) {
    extern __shared__ float lds[];
    float* sEA = lds;                      // 256 * (FE+1)
    float* su = lds + 256 * (FE + 1);      // 3 * FE
    int t = threadIdx.x;
    int ldE = FE + 1;

    for (int i = t; i < 3 * FE; i += 256) su[i] = u[i];

    const float4* ea4 = (const float4*)ea;
    int per_block = 64 * FE;  // 256*FE/4 float4s
    size_t base4 = (size_t)blockIdx.x * per_block;
    size_t tot4 = (size_t)E * FE / 4;
    for (int i = t; i < per_block; i += 256) {
        size_t g4 = base4 + i;
        if (g4 < tot4) {
            float4 v = ea4[g4];
            int g = i * 4;
            int e_loc = g / FE, f = g % FE;
            float* p = &sEA[e_loc * ldE + f];
            p[0] = v.x; p[1] = v.y; p[2] = v.z; p[3] = v.w;
        }
    }
    __syncthreads();

    int e = blockIdx.x * 256 + t;
    if (e < E) {
        float a0 = 0.f, a1 = 0.f, a2 = 0.f;
        const float* row = &sEA[t * ldE];
        for (int f = 0; f < FE; ++f) {
            float v = row[f];
            a0 += v * su[f];
            a1 += v * su[FE + f];
            a2 += v * su[2 * FE + f];
        }
        int src = ei[e], dst = ei[E + e];
        int pos = atomicAdd(&fill[dst], 1);
        rec[pos] = make_float4(__int_as_float(src), a0, a1, a2);
    }
}

// ---------------- fill self-loop record slots ----------------
__global__ void k_self(const int* __restrict__ row_ptr, float4* rec,
                       const float* __restrict__ sE, int N) {
    int n = blockIdx.x * blockDim.x + threadIdx.x;
    if (n < N) {
        rec[row_ptr[n]] = make_float4(__int_as_float(n), sE[0], sE[1], sE[2]);
    }
}

// ---------------- h = x @ W ; as_n = h.a_s ; ad_n = h.a_d ----------------
__global__ void k_gemm(const float* __restrict__ x, const float* __restrict__ W,
                       const float* __restrict__ a_s, const float* __restrict__ a_d,
                       float* __restrict__ h, float* __restrict__ as_n,
                       float* __restrict__ ad_n, int N, int K) {
    extern __shared__ float lds[];
    float* Ws = lds;            // K*64
    float* Xs = lds + K * HD;   // 16*K
    int t = threadIdx.x;
    int nb = blockIdx.x * 16;
    for (int i = t; i < K * HD; i += 256) Ws[i] = W[i];
    for (int i = t; i < 16 * K; i += 256) {
        int r = i / K, c = i % K;
        int gr = nb + r;
        if (gr >= N) gr = N - 1;
        Xs[i] = x[(size_t)gr * K + c];
    }
    __syncthreads();
    int c = t & 63, w = t >> 6;
    float acc[4] = {0.f, 0.f, 0.f, 0.f};
    for (int k = 0; k < K; ++k) {
        float wv = Ws[k * HD + c];
#pragma unroll
        for (int j = 0; j < 4; ++j) acc[j] += Xs[(w * 4 + j) * K + k] * wv;
    }
    float asv = a_s[c], adv = a_d[c];
#pragma unroll
    for (int j = 0; j < 4; ++j) {
        int n = nb + w * 4 + j;
        if (n >= N) continue;
        h[(size_t)n * HD + c] = acc[j];
        float vs = acc[j] * asv, vd = acc[j] * adv;
        for (int d = 32; d; d >>= 1) {
            vs += __shfl_down(vs, d, 64);
            vd += __shfl_down(vd, d, 64);
        }
        if (c == 0) { as_n[n] = vs; ad_n[n] = vd; }
    }
}

// ---------------- per-node aggregation: lane-parallel alpha + shuffle-broadcast FMA ----------------
__global__ void k_aggr(const float* __restrict__ h, const float* __restrict__ as_n,
                       const float* __restrict__ ad_n, const int* __restrict__ row_ptr,
                       const float4* __restrict__ rec, int l,
                       const float* __restrict__ b, float* __restrict__ x_out,
                       float* __restrict__ emb, int N, int first) {
    int wave = threadIdx.x >> 6, lane = threadIdx.x & 63;
    int n = blockIdx.x * 4 + wave;
    if (n >= N) return;
    int base = row_ptr[n], end = row_ptr[n + 1];
    float adv = ad_n[n];
    float m = -INFINITY, d = 0.f, acc = 0.f;

    for (int c = base; c < end; c += 64) {
        int cnt = min(64, end - c);
        // phase 1: lane i computes alpha for edge c+i (coalesced rec load)
        float a = -INFINITY;
        int s = 0;
        if (lane < cnt) {
            float4 r = rec[c + lane];
            s = __float_as_int(r.x);
            float aE = (l == 0) ? r.y : (l == 1) ? r.z : r.w;
            a = as_n[s] + adv + aE;
            a = (a > 0.f) ? a : 0.2f * a;
        }
        // wave max + sum-of-exp (butterfly: every lane gets the result)
        float mc = a;
#pragma unroll
        for (int dd = 32; dd; dd >>= 1) mc = fmaxf(mc, __shfl_xor(mc, dd, 64));
        float mn = fmaxf(m, mc);
        float w = (lane < cnt) ? __expf(a - mn) : 0.f;
        float dc = w;
#pragma unroll
        for (int dd = 32; dd; dd >>= 1) dc += __shfl_xor(dc, dd, 64);
        float sc = __expf(m - mn);  // first chunk: exp(-inf) = 0
        d = d * sc + dc;
        acc = acc * sc;
        m = mn;
        // phase 2: lane = feature; broadcast (src, w) per edge, 4 gathers in flight
        int j = 0;
        for (; j + 3 < cnt; j += 4) {
            int s0 = __shfl(s, j, 64), s1 = __shfl(s, j + 1, 64),
                s2 = __shfl(s, j + 2, 64), s3 = __shfl(s, j + 3, 64);
            float w0 = __shfl(w, j, 64), w1 = __shfl(w, j + 1, 64),
                  w2 = __shfl(w, j + 2, 64), w3 = __shfl(w, j + 3, 64);
            float h0 = h[(size_t)s0 * HD + lane];
            float h1 = h[(size_t)s1 * HD + lane];
            float h2 = h[(size_t)s2 * HD + lane];
            float h3 = h[(size_t)s3 * HD + lane];
            acc += w0 * h0; acc += w1 * h1; acc += w2 * h2; acc += w3 * h3;
        }
        for (; j < cnt; ++j) {
            int sj = __shfl(s, j, 64);
            float wj = __shfl(w, j, 64);
            acc += wj * h[(size_t)sj * HD + lane];
        }
    }

    float out = acc / (d + 1e-16f) + b[lane];
    float v = (out > 0.f) ? out : expm1f(out);
    x_out[(size_t)n * HD + lane] = v;
    if (first) emb[(size_t)n * HD + lane] = v;
    else emb[(size_t)n * HD + lane] += v;
}

// ---------------- column sums of emb -> gacc (atomic) ----------------
__global__ void k_red(const float* __restrict__ emb, float* gacc, int N) {
    __shared__ float lds[256];
    int f = threadIdx.x & 63, w = threadIdx.x >> 6;
    float s = 0.f;
    for (int n = blockIdx.x * 4 + w; n < N; n += gridDim.x * 4)
        s += emb[(size_t)n * HD + f];
    lds[threadIdx.x] = s;
    __syncthreads();
    if (w == 0) {
        float v = lds[f] + lds[64 + f] + lds[128 + f] + lds[192 + f];
        atomicAdd(&gacc[f], v);
    }
}

__global__ void k_div(const float* __restrict__ gacc, float* out, int N) {
    int f = threadIdx.x;
    if (f < HD) out[(size_t)N * HD + f] = gacc[f] / (float)N;
}

extern "C" void kernel_launch(void* const* d_in, const int* in_sizes, int n_in,
                              void* d_out, int out_size, void* d_ws, size_t ws_size,
                              hipStream_t stream) {
    const float* x = (const float*)d_in[0];
    const int* ei = (const int*)d_in[1];
    const float* ea = (const float*)d_in[2];

    const int FIN = in_sizes[3] / HD;       // W1 is [F_IN, 64]
    const int N = in_sizes[0] / FIN;
    const int E = in_sizes[1] / 2;
    const int FE = in_sizes[2] / E;
    const int Ep = E + N;
    const int NB = 1024;                    // colsum partial blocks

    const float* W[3];  const float* as_[3]; const float* ad_[3];
    const float* We[3]; const float* ae_[3]; const float* bb[3];
    for (int l = 0; l < 3; ++l) {
        W[l]  = (const float*)d_in[3 + 6 * l + 0];
        as_[l] = (const float*)d_in[3 + 6 * l + 1];
        ad_[l] = (const float*)d_in[3 + 6 * l + 2];
        We[l] = (const float*)d_in[3 + 6 * l + 3];
        ae_[l] = (const float*)d_in[3 + 6 * l + 4];
        bb[l] = (const float*)d_in[3 + 6 * l + 5];
    }

    // ---- workspace layout (bytes, 256-aligned) ----
    char* ws = (char*)d_ws;
    size_t off = 0;
    auto alloc = [&](size_t bytes) {
        void* p = ws + off;
        off += (bytes + 255) & ~(size_t)255;
        return p;
    };
    float*  h      = (float*)alloc((size_t)N * HD * 4);
    float*  x_cur  = (float*)alloc((size_t)N * HD * 4);
    float*  as_n   = (float*)alloc((size_t)N * 4);
    float*  ad_n   = (float*)alloc((size_t)N * 4);
    int*    cnt    = (int*)alloc((size_t)N * 4);
    int*    rowp   = (int*)alloc((size_t)(N + 1) * 4);
    int*    fill   = (int*)alloc((size_t)N * 4);
    int*    pre    = (int*)alloc((size_t)N * 4);
    int*    bsums  = (int*)alloc(256 * 4);
    int*    total  = (int*)alloc(4);
    float4* rec    = (float4*)alloc((size_t)Ep * 16);
    float*  u      = (float*)alloc((size_t)3 * FE * 4);
    float*  partials = (float*)alloc((size_t)NB * FE * 4);
    float*  sE     = (float*)alloc(3 * 4);
    float*  gacc   = (float*)alloc(HD * 4);
    (void)ws_size; (void)n_in; (void)out_size;

    float* emb = (float*)d_out;  // [N,64] node embeddings; tail 64 = graph emb

    int gN = (N + 255) / 256;
    int gE = (E + 255) / 256;
    size_t tot4 = (size_t)E * FE / 4;

    k_init<<<gN, 256, 0, stream>>>(cnt, gacc, N);
    k_u<<<1, 64, 0, stream>>>(We[0], ae_[0], We[1], ae_[1], We[2], ae_[2], u, FE);
    k_colsum<<<NB, 256, 0, stream>>>(ea, tot4, partials);
    k_u2<<<1, 256, 0, stream>>>(partials, NB, u, sE, FE, 1.0f / (float)E);
    k_hist<<<gE, 256, 0, stream>>>(ei, E, cnt);
    k_scanA<<<gN, 256, 0, stream>>>(cnt, pre, bsums, N);
    k_scanB<<<1, 256, 0, stream>>>(bsums, gN, total);
    k_scanC<<<gN, 256, 0, stream>>>(pre, bsums, total, rowp, fill, N);
    size_t sc_lds = (size_t)(256 * (FE + 1) + 3 * FE) * 4;
    k_scatter<<<gE, 256, sc_lds, stream>>>(ei, ea, u, E, FE, fill, rec);
    k_self<<<gN, 256, 0, stream>>>(rowp, rec, sE, N);

    for (int l = 0; l < 3; ++l) {
        const float* xin = (l == 0) ? x : x_cur;
        int K = (l == 0) ? FIN : HD;
        size_t ldsz = (size_t)(K * HD + 16 * K) * 4;
        k_gemm<<<(N + 15) / 16, 256, ldsz, stream>>>(xin, W[l], as_[l], ad_[l],
                                                     h, as_n, ad_n, N, K);
        k_aggr<<<(N + 3) / 4, 256, 0, stream>>>(h, as_n, ad_n, rowp, rec, l,
                                                bb[l], x_cur, emb, N, (l == 0) ? 1 : 0);
    }

    k_red<<<256, 256, 0, stream>>>(emb, gacc, N);
    k_div<<<1, 64, 0, stream>>>(gacc, emb, N);
}

// Round 6
// 480.169 us; speedup vs baseline: 2.4836x; 1.0501x over previous
//
#include <hip/hip_runtime.h>
#include <hip/hip_fp16.h>
#include <math.h>

#define HD 64  // hidden dim H

typedef unsigned long long u64;

__device__ __forceinline__ u64 pack_rec(int src, float a0, float a1, float a2) {
    return (u64)(src & 0xFFFF)
         | ((u64)__half_as_ushort(__float2half(a0)) << 16)
         | ((u64)__half_as_ushort(__float2half(a1)) << 32)
         | ((u64)__half_as_ushort(__float2half(a2)) << 48);
}

// ---------------- init: cnt=1 (self loop), zero gacc ----------------
__global__ void k_init(int* cnt, float* gacc, int N) {
    int i = blockIdx.x * blockDim.x + threadIdx.x;
    if (i < N) cnt[i] = 1;
    if (i < HD) gacc[i] = 0.f;
}

// ---------------- fused: column-sum partials of ea + in-degree histogram ----------------
__global__ void k_pre(const float* __restrict__ ea, size_t tot4, float* partials,
                      const int* __restrict__ ei, int E, int* cnt) {
    __shared__ float lds[256 * 4];
    const float4* ea4 = (const float4*)ea;
    int t = threadIdx.x;
    float4 acc = make_float4(0.f, 0.f, 0.f, 0.f);
    for (size_t i = (size_t)blockIdx.x * 256 + t; i < tot4; i += (size_t)gridDim.x * 256) {
        float4 v = ea4[i];
        acc.x += v.x; acc.y += v.y; acc.z += v.z; acc.w += v.w;
    }
    lds[t * 4 + 0] = acc.x; lds[t * 4 + 1] = acc.y;
    lds[t * 4 + 2] = acc.z; lds[t * 4 + 3] = acc.w;
    // histogram (no LDS use; overlaps with reduce)
    for (int e = blockIdx.x * 256 + t; e < E; e += gridDim.x * 256)
        atomicAdd(&cnt[ei[E + e]], 1);
    __syncthreads();
    if (t < 16) {
        int q = t >> 2, j = t & 3;  // feature = q*4 + j
        float s = 0.f;
        for (int k = 0; k < 64; ++k) s += lds[(q + k * 4) * 4 + j];
        partials[blockIdx.x * 16 + (q * 4 + j)] = s;
    }
}

// ---------------- u[l] = We_l @ ae_l ; mean_ea ; sE[l] = mean_ea . u_l ----------------
__global__ void k_u2(const float* __restrict__ partials, int NB,
                     const float* We1, const float* ae1,
                     const float* We2, const float* ae2,
                     const float* We3, const float* ae3,
                     float* u, float* sE, int FE, float invE) {
    __shared__ float red[256];
    __shared__ float uu[64];
    int t = threadIdx.x;
    if (t < 3 * FE) {
        int l = t / FE, f = t % FE;
        const float* We = (l == 0) ? We1 : (l == 1) ? We2 : We3;
        const float* ae = (l == 0) ? ae1 : (l == 1) ? ae2 : ae3;
        float s = 0.f;
        for (int hh = 0; hh < HD; ++hh) s += We[f * HD + hh] * ae[hh];
        uu[t] = s; u[t] = s;
    }
    int col = t & 15, grp = t >> 4;
    float s = 0.f;
    for (int b = grp; b < NB; b += 16) s += partials[b * FE + col];
    red[t] = s;
    __syncthreads();
    if (t < 16) {
        float v = 0.f;
        for (int g = 0; g < 16; ++g) v += red[g * 16 + t];
        red[t] = v * invE;  // mean_ea[col]
    }
    __syncthreads();
    if (t < 3) {
        float a = 0.f;
        for (int f = 0; f < FE; ++f) a += red[f] * uu[t * FE + f];
        sE[t] = a;  // self-loop alpha_e for layer t
    }
}

// ---------------- 3-stage parallel exclusive scan over cnt ----------------
__global__ void k_scanA(const int* __restrict__ cnt, int* pre, int* blocksums, int N) {
    __shared__ int lds[256];
    int t = threadIdx.x;
    int n = blockIdx.x * 256 + t;
    int v = (n < N) ? cnt[n] : 0;
    lds[t] = v;
    __syncthreads();
    for (int d = 1; d < 256; d <<= 1) {
        int x = (t >= d) ? lds[t - d] : 0;
        __syncthreads();
        lds[t] += x;
        __syncthreads();
    }
    if (n < N) pre[n] = lds[t] - v;  // exclusive within block
    if (t == 255) blocksums[blockIdx.x] = lds[255];
}

__global__ void k_scanB(int* blocksums, int NBLK, int* total) {
    __shared__ int lds[256];
    int t = threadIdx.x;
    int v = (t < NBLK) ? blocksums[t] : 0;
    lds[t] = v;
    __syncthreads();
    for (int d = 1; d < 256; d <<= 1) {
        int x = (t >= d) ? lds[t - d] : 0;
        __syncthreads();
        lds[t] += x;
        __syncthreads();
    }
    if (t < NBLK) blocksums[t] = lds[t] - v;  // exclusive block offsets
    if (t == 255) *total = lds[255];
}

// C: combine -> row_ptr, fill = row_ptr+1, AND write self-loop record
__global__ void k_scanC(const int* __restrict__ pre, const int* __restrict__ blocksums,
                        const int* __restrict__ total, int* row_ptr, int* fill,
                        u64* __restrict__ rec, const float* __restrict__ sE, int N) {
    int n = blockIdx.x * 256 + threadIdx.x;
    if (n < N) {
        int r = pre[n] + blocksums[blockIdx.x];
        row_ptr[n] = r;
        fill[n] = r + 1;
        rec[r] = pack_rec(n, sE[0], sE[1], sE[2]);
    }
    if (n == 0) row_ptr[N] = *total;
}

// ---------------- scatter: LDS-staged alpha dots; ONE 8B record/edge ----------------
__global__ void k_scatter(const int* __restrict__ ei, const float* __restrict__ ea,
                          const float* __restrict__ u, int E, int FE,
                          int* fill, u64* __restrict__ rec) {
    extern __shared__ float lds[];
    float* sEA = lds;                      // 256 * (FE+1)
    float* su = lds + 256 * (FE + 1);      // 3 * FE
    int t = threadIdx.x;
    int ldE = FE + 1;

    for (int i = t; i < 3 * FE; i += 256) su[i] = u[i];

    const float4* ea4 = (const float4*)ea;
    int per_block = 64 * FE;  // 256*FE/4 float4s
    size_t base4 = (size_t)blockIdx.x * per_block;
    size_t tot4 = (size_t)E * FE / 4;
    for (int i = t; i < per_block; i += 256) {
        size_t g4 = base4 + i;
        if (g4 < tot4) {
            float4 v = ea4[g4];
            int g = i * 4;
            int e_loc = g / FE, f = g % FE;
            float* p = &sEA[e_loc * ldE + f];
            p[0] = v.x; p[1] = v.y; p[2] = v.z; p[3] = v.w;
        }
    }
    __syncthreads();

    int e = blockIdx.x * 256 + t;
    if (e < E) {
        float a0 = 0.f, a1 = 0.f, a2 = 0.f;
        const float* row = &sEA[t * ldE];
        for (int f = 0; f < FE; ++f) {
            float v = row[f];
            a0 += v * su[f];
            a1 += v * su[FE + f];
            a2 += v * su[2 * FE + f];
        }
        int src = ei[e], dst = ei[E + e];
        int pos = atomicAdd(&fill[dst], 1);
        rec[pos] = pack_rec(src, a0, a1, a2);
    }
}

// ---------------- h(f16) = x @ W ; as_n = h.a_s ; ad_n = h.a_d ----------------
__global__ void k_gemm(const float* __restrict__ x, const float* __restrict__ W,
                       const float* __restrict__ a_s, const float* __restrict__ a_d,
                       __half* __restrict__ h, float* __restrict__ as_n,
                       float* __restrict__ ad_n, int N, int K) {
    extern __shared__ float lds[];
    float* Ws = lds;            // K*64
    float* Xs = lds + K * HD;   // 16*K
    int t = threadIdx.x;
    int nb = blockIdx.x * 16;
    for (int i = t; i < K * HD; i += 256) Ws[i] = W[i];
    for (int i = t; i < 16 * K; i += 256) {
        int r = i / K, c = i % K;
        int gr = nb + r;
        if (gr >= N) gr = N - 1;
        Xs[i] = x[(size_t)gr * K + c];
    }
    __syncthreads();
    int c = t & 63, w = t >> 6;
    float acc[4] = {0.f, 0.f, 0.f, 0.f};
    for (int k = 0; k < K; ++k) {
        float wv = Ws[k * HD + c];
#pragma unroll
        for (int j = 0; j < 4; ++j) acc[j] += Xs[(w * 4 + j) * K + k] * wv;
    }
    float asv = a_s[c], adv = a_d[c];
#pragma unroll
    for (int j = 0; j < 4; ++j) {
        int n = nb + w * 4 + j;
        if (n >= N) continue;
        h[(size_t)n * HD + c] = __float2half(acc[j]);
        float vs = acc[j] * asv, vd = acc[j] * adv;
        for (int d = 32; d; d >>= 1) {
            vs += __shfl_down(vs, d, 64);
            vd += __shfl_down(vd, d, 64);
        }
        if (c == 0) { as_n[n] = vs; ad_n[n] = vd; }
    }
}

// ---------------- per-node aggregation: lane-parallel alpha + shuffle-broadcast FMA ----------------
__global__ void k_aggr(const __half* __restrict__ h, const float* __restrict__ as_n,
                       const float* __restrict__ ad_n, const int* __restrict__ row_ptr,
                       const u64* __restrict__ rec, int l,
                       const float* __restrict__ b, float* __restrict__ x_out,
                       float* __restrict__ emb, int N, int first) {
    int wave = threadIdx.x >> 6, lane = threadIdx.x & 63;
    int n = blockIdx.x * 4 + wave;
    if (n >= N) return;
    int base = row_ptr[n], end = row_ptr[n + 1];
    float adv = ad_n[n];
    const int shift = 16 * (l + 1);
    float m = -INFINITY, d = 0.f, acc = 0.f;

    for (int c = base; c < end; c += 64) {
        int cnt = min(64, end - c);
        // phase 1: lane i computes alpha for edge c+i (coalesced 8B rec load)
        float a = -INFINITY;
        int s = 0;
        if (lane < cnt) {
            u64 r = rec[c + lane];
            s = (int)(r & 0xFFFFull);
            float aE = __half2float(__ushort_as_half((unsigned short)(r >> shift)));
            a = as_n[s] + adv + aE;
            a = (a > 0.f) ? a : 0.2f * a;
        }
        // wave max + sum-of-exp (butterfly: every lane gets the result)
        float mc = a;
#pragma unroll
        for (int dd = 32; dd; dd >>= 1) mc = fmaxf(mc, __shfl_xor(mc, dd, 64));
        float mn = fmaxf(m, mc);
        float w = (lane < cnt) ? __expf(a - mn) : 0.f;
        float dc = w;
#pragma unroll
        for (int dd = 32; dd; dd >>= 1) dc += __shfl_xor(dc, dd, 64);
        float sc = __expf(m - mn);  // first chunk: exp(-inf) = 0
        d = d * sc + dc;
        acc = acc * sc;
        m = mn;
        // phase 2: lane = feature; broadcast (src, w) per edge, 4 gathers in flight
        int j = 0;
        for (; j + 3 < cnt; j += 4) {
            int s0 = __shfl(s, j, 64), s1 = __shfl(s, j + 1, 64),
                s2 = __shfl(s, j + 2, 64), s3 = __shfl(s, j + 3, 64);
            float w0 = __shfl(w, j, 64), w1 = __shfl(w, j + 1, 64),
                  w2 = __shfl(w, j + 2, 64), w3 = __shfl(w, j + 3, 64);
            float h0 = __half2float(h[(size_t)s0 * HD + lane]);
            float h1 = __half2float(h[(size_t)s1 * HD + lane]);
            float h2 = __half2float(h[(size_t)s2 * HD + lane]);
            float h3 = __half2float(h[(size_t)s3 * HD + lane]);
            acc += w0 * h0; acc += w1 * h1; acc += w2 * h2; acc += w3 * h3;
        }
        for (; j < cnt; ++j) {
            int sj = __shfl(s, j, 64);
            float wj = __shfl(w, j, 64);
            acc += wj * __half2float(h[(size_t)sj * HD + lane]);
        }
    }

    float out = acc / (d + 1e-16f) + b[lane];
    float v = (out > 0.f) ? out : expm1f(out);
    x_out[(size_t)n * HD + lane] = v;
    if (first) emb[(size_t)n * HD + lane] = v;
    else emb[(size_t)n * HD + lane] += v;
}

// ---------------- column sums of emb -> gacc (atomic) ----------------
__global__ void k_red(const float* __restrict__ emb, float* gacc, int N) {
    __shared__ float lds[256];
    int f = threadIdx.x & 63, w = threadIdx.x >> 6;
    float s = 0.f;
    for (int n = blockIdx.x * 4 + w; n < N; n += gridDim.x * 4)
        s += emb[(size_t)n * HD + f];
    lds[threadIdx.x] = s;
    __syncthreads();
    if (w == 0) {
        float v = lds[f] + lds[64 + f] + lds[128 + f] + lds[192 + f];
        atomicAdd(&gacc[f], v);
    }
}

__global__ void k_div(const float* __restrict__ gacc, float* out, int N) {
    int f = threadIdx.x;
    if (f < HD) out[(size_t)N * HD + f] = gacc[f] / (float)N;
}

extern "C" void kernel_launch(void* const* d_in, const int* in_sizes, int n_in,
                              void* d_out, int out_size, void* d_ws, size_t ws_size,
                              hipStream_t stream) {
    const float* x = (const float*)d_in[0];
    const int* ei = (const int*)d_in[1];
    const float* ea = (const float*)d_in[2];

    const int FIN = in_sizes[3] / HD;       // W1 is [F_IN, 64]
    const int N = in_sizes[0] / FIN;
    const int E = in_sizes[1] / 2;
    const int FE = in_sizes[2] / E;
    const int Ep = E + N;
    const int NB = 1024;                    // pre-pass blocks

    const float* W[3];  const float* as_[3]; const float* ad_[3];
    const float* We[3]; const float* ae_[3]; const float* bb[3];
    for (int l = 0; l < 3; ++l) {
        W[l]  = (const float*)d_in[3 + 6 * l + 0];
        as_[l] = (const float*)d_in[3 + 6 * l + 1];
        ad_[l] = (const float*)d_in[3 + 6 * l + 2];
        We[l] = (const float*)d_in[3 + 6 * l + 3];
        ae_[l] = (const float*)d_in[3 + 6 * l + 4];
        bb[l] = (const float*)d_in[3 + 6 * l + 5];
    }

    // ---- workspace layout (bytes, 256-aligned) ----
    char* ws = (char*)d_ws;
    size_t off = 0;
    auto alloc = [&](size_t bytes) {
        void* p = ws + off;
        off += (bytes + 255) & ~(size_t)255;
        return p;
    };
    __half* h      = (__half*)alloc((size_t)N * HD * 2);
    float*  x_cur  = (float*)alloc((size_t)N * HD * 4);
    float*  as_n   = (float*)alloc((size_t)N * 4);
    float*  ad_n   = (float*)alloc((size_t)N * 4);
    int*    cnt    = (int*)alloc((size_t)N * 4);
    int*    rowp   = (int*)alloc((size_t)(N + 1) * 4);
    int*    fill   = (int*)alloc((size_t)N * 4);
    int*    pre    = (int*)alloc((size_t)N * 4);
    int*    bsums  = (int*)alloc(256 * 4);
    int*    total  = (int*)alloc(4);
    u64*    rec    = (u64*)alloc((size_t)Ep * 8);
    float*  u      = (float*)alloc((size_t)3 * FE * 4);
    float*  partials = (float*)alloc((size_t)NB * FE * 4);
    float*  sE     = (float*)alloc(3 * 4);
    float*  gacc   = (float*)alloc(HD * 4);
    (void)ws_size; (void)n_in; (void)out_size;

    float* emb = (float*)d_out;  // [N,64] node embeddings; tail 64 = graph emb

    int gN = (N + 255) / 256;
    int gE = (E + 255) / 256;
    size_t tot4 = (size_t)E * FE / 4;

    k_init<<<gN, 256, 0, stream>>>(cnt, gacc, N);
    k_pre<<<NB, 256, 0, stream>>>(ea, tot4, partials, ei, E, cnt);
    k_u2<<<1, 256, 0, stream>>>(partials, NB, We[0], ae_[0], We[1], ae_[1],
                                We[2], ae_[2], u, sE, FE, 1.0f / (float)E);
    k_scanA<<<gN, 256, 0, stream>>>(cnt, pre, bsums, N);
    k_scanB<<<1, 256, 0, stream>>>(bsums, gN, total);
    k_scanC<<<gN, 256, 0, stream>>>(pre, bsums, total, rowp, fill, rec, sE, N);
    size_t sc_lds = (size_t)(256 * (FE + 1) + 3 * FE) * 4;
    k_scatter<<<gE, 256, sc_lds, stream>>>(ei, ea, u, E, FE, fill, rec);

    for (int l = 0; l < 3; ++l) {
        const float* xin = (l == 0) ? x : x_cur;
        int K = (l == 0) ? FIN : HD;
        size_t ldsz = (size_t)(K * HD + 16 * K) * 4;
        k_gemm<<<(N + 15) / 16, 256, ldsz, stream>>>(xin, W[l], as_[l], ad_[l],
                                                     h, as_n, ad_n, N, K);
        k_aggr<<<(N + 3) / 4, 256, 0, stream>>>(h, as_n, ad_n, rowp, rec, l,
                                                bb[l], x_cur, emb, N, (l == 0) ? 1 : 0);
    }

    k_red<<<256, 256, 0, stream>>>(emb, gacc, N);
    k_div<<<1, 64, 0, stream>>>(gacc, emb, N);
}

// Round 8
// 438.873 us; speedup vs baseline: 2.7173x; 1.0941x over previous
//
#include <hip/hip_runtime.h>
#include <hip/hip_fp16.h>
#include <math.h>

#define HD 64  // hidden dim H

typedef unsigned long long u64;
typedef _Float16 f16;
typedef _Float16 f16x8 __attribute__((ext_vector_type(8)));
typedef float f32x4 __attribute__((ext_vector_type(4)));

__device__ __forceinline__ u64 pack_rec(int src, float a0, float a1, float a2) {
    return (u64)(src & 0xFFFF)
         | ((u64)__half_as_ushort(__float2half(a0)) << 16)
         | ((u64)__half_as_ushort(__float2half(a1)) << 32)
         | ((u64)__half_as_ushort(__float2half(a2)) << 48);
}

// ---------------- init: cnt=1 (self loop), zero gacc ----------------
__global__ void k_init(int* cnt, float* gacc, int N) {
    int i = blockIdx.x * blockDim.x + threadIdx.x;
    if (i < N) cnt[i] = 1;
    if (i < HD) gacc[i] = 0.f;
}

// ---------------- fused: column-sum partials of ea + in-degree histogram ----------------
__global__ void k_pre(const float* __restrict__ ea, size_t tot4, float* partials,
                      const int* __restrict__ ei, int E, int* cnt) {
    __shared__ float lds[256 * 4];
    const float4* ea4 = (const float4*)ea;
    int t = threadIdx.x;
    float4 acc = make_float4(0.f, 0.f, 0.f, 0.f);
    for (size_t i = (size_t)blockIdx.x * 256 + t; i < tot4; i += (size_t)gridDim.x * 256) {
        float4 v = ea4[i];
        acc.x += v.x; acc.y += v.y; acc.z += v.z; acc.w += v.w;
    }
    lds[t * 4 + 0] = acc.x; lds[t * 4 + 1] = acc.y;
    lds[t * 4 + 2] = acc.z; lds[t * 4 + 3] = acc.w;
    for (int e = blockIdx.x * 256 + t; e < E; e += gridDim.x * 256)
        atomicAdd(&cnt[ei[E + e]], 1);
    __syncthreads();
    if (t < 16) {
        int q = t >> 2, j = t & 3;  // feature = q*4 + j
        float s = 0.f;
        for (int k = 0; k < 64; ++k) s += lds[(q + k * 4) * 4 + j];
        partials[blockIdx.x * 16 + (q * 4 + j)] = s;
    }
}

// ---------------- u[l] = We_l @ ae_l ; mean_ea ; sE[l] = mean_ea . u_l ----------------
__global__ void k_u2(const float* __restrict__ partials, int NB,
                     const float* We1, const float* ae1,
                     const float* We2, const float* ae2,
                     const float* We3, const float* ae3,
                     float* u, float* sE, int FE, float invE) {
    __shared__ float red[256];
    __shared__ float uu[64];
    int t = threadIdx.x;
    if (t < 3 * FE) {
        int l = t / FE, f = t % FE;
        const float* We = (l == 0) ? We1 : (l == 1) ? We2 : We3;
        const float* ae = (l == 0) ? ae1 : (l == 1) ? ae2 : ae3;
        float s = 0.f;
        for (int hh = 0; hh < HD; ++hh) s += We[f * HD + hh] * ae[hh];
        uu[t] = s; u[t] = s;
    }
    int col = t & 15, grp = t >> 4;
    float s = 0.f;
    for (int b = grp; b < NB; b += 16) s += partials[b * FE + col];
    red[t] = s;
    __syncthreads();
    if (t < 16) {
        float v = 0.f;
        for (int g = 0; g < 16; ++g) v += red[g * 16 + t];
        red[t] = v * invE;  // mean_ea[col]
    }
    __syncthreads();
    if (t < 3) {
        float a = 0.f;
        for (int f = 0; f < FE; ++f) a += red[f] * uu[t * FE + f];
        sE[t] = a;  // self-loop alpha_e for layer t
    }
}

// ---------------- 3-stage parallel exclusive scan over cnt ----------------
__global__ void k_scanA(const int* __restrict__ cnt, int* pre, int* blocksums, int N) {
    __shared__ int lds[256];
    int t = threadIdx.x;
    int n = blockIdx.x * 256 + t;
    int v = (n < N) ? cnt[n] : 0;
    lds[t] = v;
    __syncthreads();
    for (int d = 1; d < 256; d <<= 1) {
        int x = (t >= d) ? lds[t - d] : 0;
        __syncthreads();
        lds[t] += x;
        __syncthreads();
    }
    if (n < N) pre[n] = lds[t] - v;
    if (t == 255) blocksums[blockIdx.x] = lds[255];
}

__global__ void k_scanB(int* blocksums, int NBLK, int* total) {
    __shared__ int lds[256];
    int t = threadIdx.x;
    int v = (t < NBLK) ? blocksums[t] : 0;
    lds[t] = v;
    __syncthreads();
    for (int d = 1; d < 256; d <<= 1) {
        int x = (t >= d) ? lds[t - d] : 0;
        __syncthreads();
        lds[t] += x;
        __syncthreads();
    }
    if (t < NBLK) blocksums[t] = lds[t] - v;
    if (t == 255) *total = lds[255];
}

// C: combine -> row_ptr, fill = row_ptr+1, AND write self-loop record
__global__ void k_scanC(const int* __restrict__ pre, const int* __restrict__ blocksums,
                        const int* __restrict__ total, int* row_ptr, int* fill,
                        u64* __restrict__ rec, const float* __restrict__ sE, int N) {
    int n = blockIdx.x * 256 + threadIdx.x;
    if (n < N) {
        int r = pre[n] + blocksums[blockIdx.x];
        row_ptr[n] = r;
        fill[n] = r + 1;
        rec[r] = pack_rec(n, sE[0], sE[1], sE[2]);
    }
    if (n == 0) row_ptr[N] = *total;
}

// ---------------- scatter: LDS-staged alpha dots; ONE 8B record/edge ----------------
__global__ void k_scatter(const int* __restrict__ ei, const float* __restrict__ ea,
                          const float* __restrict__ u, int E, int FE,
                          int* fill, u64* __restrict__ rec) {
    extern __shared__ float lds[];
    float* sEA = lds;                      // 256 * (FE+1)
    float* su = lds + 256 * (FE + 1);      // 3 * FE
    int t = threadIdx.x;
    int ldE = FE + 1;

    for (int i = t; i < 3 * FE; i += 256) su[i] = u[i];

    const float4* ea4 = (const float4*)ea;
    int per_block = 64 * FE;
    size_t base4 = (size_t)blockIdx.x * per_block;
    size_t tot4 = (size_t)E * FE / 4;
    for (int i = t; i < per_block; i += 256) {
        size_t g4 = base4 + i;
        if (g4 < tot4) {
            float4 v = ea4[g4];
            int g = i * 4;
            int e_loc = g / FE, f = g % FE;
            float* p = &sEA[e_loc * ldE + f];
            p[0] = v.x; p[1] = v.y; p[2] = v.z; p[3] = v.w;
        }
    }
    __syncthreads();

    int e = blockIdx.x * 256 + t;
    if (e < E) {
        float a0 = 0.f, a1 = 0.f, a2 = 0.f;
        const float* row = &sEA[t * ldE];
        for (int f = 0; f < FE; ++f) {
            float v = row[f];
            a0 += v * su[f];
            a1 += v * su[FE + f];
            a2 += v * su[2 * FE + f];
        }
        int src = ei[e], dst = ei[E + e];
        int pos = atomicAdd(&fill[dst], 1);
        rec[pos] = pack_rec(src, a0, a1, a2);
    }
}

// ---------------- MFMA GEMM: h(f16) = x @ W ; as_n = h.a_s ; ad_n = h.a_d ----------------
// block = 256 threads (4 waves), 64 nodes/block, 64 cols, K in {128,64}
// LDS: xs[64][K+8] f16, wt[64][K+8] f16 (wt[c][k] = W[k][c]); epilogue reuses xs as ht[64][72]
__global__ void k_gemm(const float* __restrict__ x, const float* __restrict__ W,
                       const float* __restrict__ a_s, const float* __restrict__ a_d,
                       __half* __restrict__ h, float* __restrict__ as_n,
                       float* __restrict__ ad_n, int N, int K) {
    extern __shared__ char smem[];
    const int SK = K + 8;
    f16* xs = (f16*)smem;          // 64*SK
    f16* wt = xs + 64 * SK;        // 64*SK
    int t = threadIdx.x;
    int nb = blockIdx.x * 64;

    // stage x tile (fp32 -> f16), coalesced float4 reads
    int nK4 = K >> 2;
    for (int i = t; i < 64 * nK4; i += 256) {
        int row = i / nK4, c4 = i % nK4;
        int gr = nb + row; if (gr >= N) gr = N - 1;
        float4 v = ((const float4*)(x + (size_t)gr * K))[c4];
        f16* p = &xs[row * SK + c4 * 4];
        p[0] = (f16)v.x; p[1] = (f16)v.y; p[2] = (f16)v.z; p[3] = (f16)v.w;
    }
    // stage W transposed (coalesced global read)
    for (int i = t; i < K * 64; i += 256) {
        int k = i >> 6, c = i & 63;
        wt[c * SK + k] = (f16)W[i];
    }
    __syncthreads();

    int wv = t >> 6, lane = t & 63;
    int m = lane & 15, quad = lane >> 4;
    int rowA = wv * 16 + m;

    f32x4 acc[4];
#pragma unroll
    for (int ct = 0; ct < 4; ++ct) acc[ct] = (f32x4){0.f, 0.f, 0.f, 0.f};

    for (int ks = 0; ks < (K >> 5); ++ks) {
        f16x8 a = *(const f16x8*)&xs[rowA * SK + ks * 32 + quad * 8];
#pragma unroll
        for (int ct = 0; ct < 4; ++ct) {
            f16x8 bf = *(const f16x8*)&wt[(ct * 16 + m) * SK + ks * 32 + quad * 8];
            acc[ct] = __builtin_amdgcn_mfma_f32_16x16x32_f16(a, bf, acc[ct], 0, 0, 0);
        }
    }

    __syncthreads();  // done reading xs/wt; reuse xs as ht
    f16* ht = xs;
    const int HS = 72;
#pragma unroll
    for (int ct = 0; ct < 4; ++ct)
#pragma unroll
        for (int r = 0; r < 4; ++r) {
            int rl = wv * 16 + quad * 4 + r;
            ht[rl * HS + ct * 16 + m] = (f16)acc[ct][r];
        }
    __syncthreads();

    // coalesced global write of h (f16): 4 threads/row, 16 halves each (2 x 16B)
    {
        int row = t >> 2, cb = (t & 3) * 16;
        int gr = nb + row;
        if (gr < N) {
            ulonglong2 v0 = *(const ulonglong2*)&ht[row * HS + cb];
            ulonglong2 v1 = *(const ulonglong2*)&ht[row * HS + cb + 8];
            *(ulonglong2*)(h + (size_t)gr * HD + cb) = v0;
            *(ulonglong2*)(h + (size_t)gr * HD + cb + 8) = v1;
        }
    }
    // per-node dots with a_s, a_d (wave handles 16 rows)
    float ac = a_s[lane], adc = a_d[lane];
    for (int rr = 0; rr < 16; ++rr) {
        int row = wv * 16 + rr, gr = nb + row;
        float v = (float)ht[row * HS + lane];
        float vs = v * ac, vd = v * adc;
#pragma unroll
        for (int dd = 32; dd; dd >>= 1) {
            vs += __shfl_down(vs, dd, 64);
            vd += __shfl_down(vd, dd, 64);
        }
        if (lane == 0 && gr < N) { as_n[gr] = vs; ad_n[gr] = vd; }
    }
}

// ---------------- per-node aggregation: lane-parallel alpha + shuffle-broadcast FMA ----------------
__global__ void k_aggr(const __half* __restrict__ h, const float* __restrict__ as_n,
                       const float* __restrict__ ad_n, const int* __restrict__ row_ptr,
                       const u64* __restrict__ rec, int l,
                       const float* __restrict__ b, float* __restrict__ x_out,
                       float* __restrict__ emb, int N, int first) {
    int wave = threadIdx.x >> 6, lane = threadIdx.x & 63;
    int n = blockIdx.x * 4 + wave;
    if (n >= N) return;
    int base = row_ptr[n], end = row_ptr[n + 1];
    float adv = ad_n[n];
    const int shift = 16 * (l + 1);
    float m = -INFINITY, d = 0.f, acc = 0.f;

    for (int c = base; c < end; c += 64) {
        int cnt = min(64, end - c);
        float a = -INFINITY;
        int s = 0;
        if (lane < cnt) {
            u64 r = rec[c + lane];
            s = (int)(r & 0xFFFFull);
            float aE = __half2float(__ushort_as_half((unsigned short)(r >> shift)));
            a = as_n[s] + adv + aE;
            a = (a > 0.f) ? a : 0.2f * a;
        }
        float mc = a;
#pragma unroll
        for (int dd = 32; dd; dd >>= 1) mc = fmaxf(mc, __shfl_xor(mc, dd, 64));
        float mn = fmaxf(m, mc);
        float w = (lane < cnt) ? __expf(a - mn) : 0.f;
        float dc = w;
#pragma unroll
        for (int dd = 32; dd; dd >>= 1) dc += __shfl_xor(dc, dd, 64);
        float sc = __expf(m - mn);
        d = d * sc + dc;
        acc = acc * sc;
        m = mn;
        int j = 0;
        for (; j + 3 < cnt; j += 4) {
            int s0 = __shfl(s, j, 64), s1 = __shfl(s, j + 1, 64),
                s2 = __shfl(s, j + 2, 64), s3 = __shfl(s, j + 3, 64);
            float w0 = __shfl(w, j, 64), w1 = __shfl(w, j + 1, 64),
                  w2 = __shfl(w, j + 2, 64), w3 = __shfl(w, j + 3, 64);
            float h0 = __half2float(h[(size_t)s0 * HD + lane]);
            float h1 = __half2float(h[(size_t)s1 * HD + lane]);
            float h2 = __half2float(h[(size_t)s2 * HD + lane]);
            float h3 = __half2float(h[(size_t)s3 * HD + lane]);
            acc += w0 * h0; acc += w1 * h1; acc += w2 * h2; acc += w3 * h3;
        }
        for (; j < cnt; ++j) {
            int sj = __shfl(s, j, 64);
            float wj = __shfl(w, j, 64);
            acc += wj * __half2float(h[(size_t)sj * HD + lane]);
        }
    }

    float out = acc / (d + 1e-16f) + b[lane];
    float v = (out > 0.f) ? out : expm1f(out);
    x_out[(size_t)n * HD + lane] = v;
    if (first) emb[(size_t)n * HD + lane] = v;
    else emb[(size_t)n * HD + lane] += v;
}

// ---------------- column sums of emb -> gacc (atomic) ----------------
__global__ void k_red(const float* __restrict__ emb, float* gacc, int N) {
    __shared__ float lds[256];
    int f = threadIdx.x & 63, w = threadIdx.x >> 6;
    float s = 0.f;
    for (int n = blockIdx.x * 4 + w; n < N; n += gridDim.x * 4)
        s += emb[(size_t)n * HD + f];
    lds[threadIdx.x] = s;
    __syncthreads();
    if (w == 0) {
        float v = lds[f] + lds[64 + f] + lds[128 + f] + lds[192 + f];
        atomicAdd(&gacc[f], v);
    }
}

__global__ void k_div(const float* __restrict__ gacc, float* out, int N) {
    int f = threadIdx.x;
    if (f < HD) out[(size_t)N * HD + f] = gacc[f] / (float)N;
}

extern "C" void kernel_launch(void* const* d_in, const int* in_sizes, int n_in,
                              void* d_out, int out_size, void* d_ws, size_t ws_size,
                              hipStream_t stream) {
    const float* x = (const float*)d_in[0];
    const int* ei = (const int*)d_in[1];
    const float* ea = (const float*)d_in[2];

    const int FIN = in_sizes[3] / HD;       // W1 is [F_IN, 64]
    const int N = in_sizes[0] / FIN;
    const int E = in_sizes[1] / 2;
    const int FE = in_sizes[2] / E;
    const int Ep = E + N;
    const int NB = 1024;

    const float* W[3];  const float* as_[3]; const float* ad_[3];
    const float* We[3]; const float* ae_[3]; const float* bb[3];
    for (int l = 0; l < 3; ++l) {
        W[l]  = (const float*)d_in[3 + 6 * l + 0];
        as_[l] = (const float*)d_in[3 + 6 * l + 1];
        ad_[l] = (const float*)d_in[3 + 6 * l + 2];
        We[l] = (const float*)d_in[3 + 6 * l + 3];
        ae_[l] = (const float*)d_in[3 + 6 * l + 4];
        bb[l] = (const float*)d_in[3 + 6 * l + 5];
    }

    // ---- workspace layout (bytes, 256-aligned) ----
    char* ws = (char*)d_ws;
    size_t off = 0;
    auto alloc = [&](size_t bytes) {
        void* p = ws + off;
        off += (bytes + 255) & ~(size_t)255;
        return p;
    };
    __half* h      = (__half*)alloc((size_t)N * HD * 2);
    float*  x_cur  = (float*)alloc((size_t)N * HD * 4);
    float*  as_n   = (float*)alloc((size_t)N * 4);
    float*  ad_n   = (float*)alloc((size_t)N * 4);
    int*    cnt    = (int*)alloc((size_t)N * 4);
    int*    rowp   = (int*)alloc((size_t)(N + 1) * 4);
    int*    fill   = (int*)alloc((size_t)N * 4);
    int*    pre    = (int*)alloc((size_t)N * 4);
    int*    bsums  = (int*)alloc(256 * 4);
    int*    total  = (int*)alloc(4);
    u64*    rec    = (u64*)alloc((size_t)Ep * 8);
    float*  u      = (float*)alloc((size_t)3 * FE * 4);
    float*  partials = (float*)alloc((size_t)NB * FE * 4);
    float*  sE     = (float*)alloc(3 * 4);
    float*  gacc   = (float*)alloc(HD * 4);
    (void)ws_size; (void)n_in; (void)out_size;

    float* emb = (float*)d_out;

    int gN = (N + 255) / 256;
    int gE = (E + 255) / 256;
    size_t tot4 = (size_t)E * FE / 4;

    k_init<<<gN, 256, 0, stream>>>(cnt, gacc, N);
    k_pre<<<NB, 256, 0, stream>>>(ea, tot4, partials, ei, E, cnt);
    k_u2<<<1, 256, 0, stream>>>(partials, NB, We[0], ae_[0], We[1], ae_[1],
                                We[2], ae_[2], u, sE, FE, 1.0f / (float)E);
    k_scanA<<<gN, 256, 0, stream>>>(cnt, pre, bsums, N);
    k_scanB<<<1, 256, 0, stream>>>(bsums, gN, total);
    k_scanC<<<gN, 256, 0, stream>>>(pre, bsums, total, rowp, fill, rec, sE, N);
    size_t sc_lds = (size_t)(256 * (FE + 1) + 3 * FE) * 4;
    k_scatter<<<gE, 256, sc_lds, stream>>>(ei, ea, u, E, FE, fill, rec);

    for (int l = 0; l < 3; ++l) {
        const float* xin = (l == 0) ? x : x_cur;
        int K = (l == 0) ? FIN : HD;
        size_t ldsz = (size_t)(2 * 64 * (K + 8)) * 2;  // xs + wt, f16
        k_gemm<<<(N + 63) / 64, 256, ldsz, stream>>>(xin, W[l], as_[l], ad_[l],
                                                     h, as_n, ad_n, N, K);
        k_aggr<<<(N + 3) / 4, 256, 0, stream>>>(h, as_n, ad_n, rowp, rec, l,
                                                bb[l], x_cur, emb, N, (l == 0) ? 1 : 0);
    }

    k_red<<<256, 256, 0, stream>>>(emb, gacc, N);
    k_div<<<1, 64, 0, stream>>>(gacc, emb, N);
}